// Round 6
// baseline (7630.579 us; speedup 1.0000x reference)
//
#include <hip/hip_runtime.h>
#include <math.h>

// Problem constants
constexpr int B_ = 4, T_ = 577, N_ = 576, D_ = 1024, G_ = 48, H_ = 16;
constexpr int NEED_ = 192, L_ = 191;
constexpr int TRIU_CNT = N_ * (N_ - 1) / 2; // 165600
constexpr int NB_ = 8;                      // blocks per batch in tridiag (512 thr each)
constexpr int NBAR_ = 640;                  // barrier slots per batch (1 per step)

// ---------------- workspace layout (bytes) ----------------
constexpr size_t OF_MSIG = 0;                                    // f32 B*N*D (dead after GEMM; aliased: invit scratch @0, pv @8MB)
constexpr size_t OF_SIM  = OF_MSIG + (size_t)B_*N_*D_*4;
constexpr size_t OF_A    = OF_SIM  + (size_t)B_*N_*N_*4;         // f64 Gram (rows also hold archived reflectors)
constexpr size_t OF_MS   = OF_A    + (size_t)B_*N_*N_*8;         // f64 sigmoid row sums
constexpr size_t OF_INVN = OF_MS   + (size_t)B_*N_*8;            // f64 1/norm of raw hs rows
constexpr size_t OF_CLS  = OF_INVN + (size_t)B_*N_*8;            // f32 cls attention sums
constexpr size_t OF_DT   = OF_CLS  + (size_t)B_*N_*4;            // f64 tridiag diagonal
constexpr size_t OF_ET   = OF_DT   + (size_t)B_*N_*8;            // f64 tridiag off-diagonal
constexpr size_t OF_TAU  = OF_ET   + (size_t)B_*N_*8;            // f64 Householder taus
constexpr size_t OF_EVAL = OF_TAU  + (size_t)B_*N_*8;            // f64 top-48 eigenvalues (descending)
constexpr size_t OF_Z    = OF_EVAL + (size_t)B_*G_*8;            // f64 eigenvectors [b][q][i]
constexpr size_t OF_PART = OF_Z    + (size_t)B_*G_*N_*8;         // f64 simmean partials B*36
constexpr size_t OF_THR  = OF_PART + (size_t)B_*36*8;            // f32 thresholds (padded)
constexpr size_t OF_BEL  = OF_THR  + 64;                         // int belong
constexpr size_t OF_BAR  = OF_BEL  + (size_t)B_*N_*4;            // int barrier counters
constexpr size_t OF_FLG  = OF_BAR  + (size_t)B_*NBAR_*4;         // int (legacy, unused)
constexpr size_t OF_VB   = OF_FLG  + (size_t)B_*16*4;            // f64 (legacy, unused)
constexpr size_t OF_WB   = OF_VB   + (size_t)B_*N_*8;            // f64 wbuf ×2 (parity double-buffer)
constexpr size_t OF_SG   = OF_WB   + (size_t)B_*2*N_*8;          // f64 (legacy, unused)
constexpr size_t OF_KP   = OF_SG   + (size_t)B_*8*8;             // f64 (legacy, unused)
constexpr size_t WS_NEEDED = OF_KP + (size_t)B_*2*16*8;

// pv: pivot-row publish buffer, ×2 parity, per batch, in the dead msig region
constexpr size_t OF_PV_ALIAS = OF_MSIG + ((size_t)8 << 20);      // f64 B*2*N

__device__ __forceinline__ double blockReduceD(double x, double* red) {
  int lane = threadIdx.x & 63, wv = threadIdx.x >> 6;
  int nw = (blockDim.x + 63) >> 6;
  for (int o = 32; o > 0; o >>= 1) x += __shfl_down(x, o);
  __syncthreads();                // protect red from previous use
  if (lane == 0) red[wv] = x;
  __syncthreads();
  double t = red[0];
  for (int i = 1; i < nw; i++) t += red[i];
  return t;                       // same deterministic value on all threads/blocks
}

// 4-value block reduction in one LDS round (deterministic, identical per block)
__device__ __forceinline__ void blockReduce4(double& x0, double& x1, double& x2,
                                             double& x3, double* red) {
  int lane = threadIdx.x & 63, wv = threadIdx.x >> 6;
  int nw = (blockDim.x + 63) >> 6;
  for (int o = 32; o > 0; o >>= 1) {
    x0 += __shfl_down(x0, o); x1 += __shfl_down(x1, o);
    x2 += __shfl_down(x2, o); x3 += __shfl_down(x3, o);
  }
  __syncthreads();
  if (lane == 0) { red[wv*4+0]=x0; red[wv*4+1]=x1; red[wv*4+2]=x2; red[wv*4+3]=x3; }
  __syncthreads();
  double t0 = red[0], t1 = red[1], t2 = red[2], t3 = red[3];
  for (int i = 1; i < nw; i++) {
    t0 += red[i*4+0]; t1 += red[i*4+1]; t2 += red[i*4+2]; t3 += red[i*4+3];
  }
  x0 = t0; x1 = t1; x2 = t2; x3 = t3;
}

// coherent (agent-scope, cache-bypassing) load/store for cross-block data
__device__ __forceinline__ double cload(const double* p) {
  return __hip_atomic_load(p, __ATOMIC_RELAXED, __HIP_MEMORY_SCOPE_AGENT);
}
__device__ __forceinline__ void cstore(double* p, double x) {
  __hip_atomic_store(p, x, __ATOMIC_RELAXED, __HIP_MEMORY_SCOPE_AGENT);
}

// device barrier among the NB_ blocks of one batch (R1/R3-measured design).
__device__ __forceinline__ void gbar(int* bar, int slot, int tid) {
  __syncthreads();
  if (tid == 0) {
    __hip_atomic_fetch_add(&bar[slot], 1, __ATOMIC_RELAXED, __HIP_MEMORY_SCOPE_AGENT);
    while (__hip_atomic_load(&bar[slot], __ATOMIC_ACQUIRE, __HIP_MEMORY_SCOPE_AGENT) < NB_)
      __builtin_amdgcn_s_sleep(2);
  }
  __syncthreads();
  __asm__ volatile("" ::: "memory");
}

// -------- K1: sigmoid features, row sums, inverse norms (+ zero barrier slots) --------
__global__ void k_prep(const float* __restrict__ hs, float* __restrict__ msig,
                       double* __restrict__ ms, double* __restrict__ invn,
                       int* __restrict__ bars) {
  __shared__ double red[16];
  if (blockIdx.x == 0) {
    for (int i = threadIdx.x; i < B_ * NBAR_; i += blockDim.x) bars[i] = 0;
  }
  int bn = blockIdx.x; int b = bn / N_, n = bn % N_;
  const float* row = hs + ((size_t)b*T_ + (n+1)) * (size_t)D_;
  float* mrow = msig + (size_t)bn * D_;
  double ssig = 0.0, ssq = 0.0;
  for (int d = threadIdx.x; d < D_; d += blockDim.x) {
    float x = row[d];
    float sg = 1.0f / (1.0f + expf(-x));
    mrow[d] = sg;
    ssig += (double)sg;
    ssq  += (double)x * (double)x;
  }
  double tot_sig = blockReduceD(ssig, red);
  double tot_sq  = blockReduceD(ssq, red);
  if (threadIdx.x == 0) {
    ms[bn] = tot_sig;
    invn[bn] = 1.0 / fmax(sqrt(tot_sq), 1e-12);
  }
}

// -------- K2: cls attention sums --------
__global__ void k_cls(const float* __restrict__ attn, float* __restrict__ cls) {
  int idx = blockIdx.x * blockDim.x + threadIdx.x;
  if (idx >= B_ * N_) return;
  int b = idx / N_, n = idx % N_;
  float s = 0.0f;
  for (int h = 0; h < H_; h++)
    s += attn[(((size_t)b*H_ + h) * T_ + 0) * T_ + (1 + n)];
  cls[idx] = s;
}

// -------- K3: tiled X*X^T GEMM; mode0 -> Gram (f64), mode1 -> cosine sim (f32) --------
__global__ void k_gemm(const float* __restrict__ hs, const float* __restrict__ msig,
                       const double* __restrict__ ms, const double* __restrict__ invn,
                       double* __restrict__ Aout, float* __restrict__ sim, int mode) {
  __shared__ float As[32][17], Bs[32][17];
  int b = blockIdx.z;
  int bi0 = blockIdx.y * 32, bj0 = blockIdx.x * 32;
  const float* base = (mode == 0) ? (msig + (size_t)b*N_*D_)
                                  : (hs + ((size_t)b*T_ + 1) * (size_t)D_);
  int tid = threadIdx.x;
  int tx = tid & 15, ty = tid >> 4;
  double a00 = 0, a01 = 0, a10 = 0, a11 = 0;
  for (int k0 = 0; k0 < D_; k0 += 16) {
    int r = tid >> 4, c = tid & 15;
    As[r][c] = base[(size_t)(bi0 + r) * D_ + k0 + c];
    Bs[r][c] = base[(size_t)(bj0 + r) * D_ + k0 + c];
    int e = tid + 256; r = e >> 4; c = e & 15;
    As[r][c] = base[(size_t)(bi0 + r) * D_ + k0 + c];
    Bs[r][c] = base[(size_t)(bj0 + r) * D_ + k0 + c];
    __syncthreads();
#pragma unroll
    for (int kk = 0; kk < 16; kk++) {
      double x0 = As[2*ty][kk],   x1 = As[2*ty+1][kk];
      double y0 = Bs[2*tx][kk],   y1 = Bs[2*tx+1][kk];
      a00 += x0*y0; a01 += x0*y1; a10 += x1*y0; a11 += x1*y1;
    }
    __syncthreads();
  }
  int i0 = bi0 + 2*ty, j0 = bj0 + 2*tx;
  if (mode == 0) {
    const double* msb = ms + (size_t)b*N_;
    double* Ab = Aout + (size_t)b*N_*N_;
    const double inv1024 = 1.0 / 1024.0;
    Ab[(size_t)i0*N_ + j0]         = a00 - msb[i0]*msb[j0]*inv1024;
    Ab[(size_t)i0*N_ + j0+1]       = a01 - msb[i0]*msb[j0+1]*inv1024;
    Ab[(size_t)(i0+1)*N_ + j0]     = a10 - msb[i0+1]*msb[j0]*inv1024;
    Ab[(size_t)(i0+1)*N_ + j0+1]   = a11 - msb[i0+1]*msb[j0+1]*inv1024;
  } else {
    const double* iv = invn + (size_t)b*N_;
    float* sb = sim + (size_t)b*N_*N_;
    sb[(size_t)i0*N_ + j0]       = (float)(a00 * iv[i0]*iv[j0]);
    sb[(size_t)i0*N_ + j0+1]     = (float)(a01 * iv[i0]*iv[j0+1]);
    sb[(size_t)(i0+1)*N_ + j0]   = (float)(a10 * iv[i0+1]*iv[j0]);
    sb[(size_t)(i0+1)*N_ + j0+1] = (float)(a11 * iv[i0+1]*iv[j0+1]);
  }
}

// -------- K4: upper-triangle sum partials --------
__global__ void k_simsum(const float* __restrict__ sim, double* __restrict__ part) {
  __shared__ double red[4];
  int blk = blockIdx.x; int b = blk / 36, s = blk % 36;
  const float* sb = sim + (size_t)b*N_*N_;
  double p = 0.0;
  for (int i = s*16; i < s*16 + 16; i++) {
    const float* row = sb + (size_t)i*N_;
    for (int j = i + 1 + threadIdx.x; j < N_; j += blockDim.x) p += (double)row[j];
  }
  double t = blockReduceD(p, red);
  if (threadIdx.x == 0) part[blk] = t;
}

__global__ void k_thr(const double* __restrict__ part, float* __restrict__ thrF) {
  int b = threadIdx.x;
  if (b < B_) {
    double s = 0.0;
    for (int i = 0; i < 36; i++) s += part[b*36 + i];
    thrF[b] = 6.0f * (float)(s / (double)TRIU_CNT);
  }
}

// -------- K5: multi-block Householder tridiagonalization --------
// R5-verified structure (8 blocks x 512 thr, ONE gbar/step, LDS pivot-row
// replicas, fused phase-D algebra, single blockReduce4, double2 phase B,
// post-barrier reflector archive, nx0s x0 routing). UNCHANGED this round.
__global__ __launch_bounds__(512) void k_tridiag_mb(double* __restrict__ Aall,
    double* __restrict__ dT, double* __restrict__ eT, double* __restrict__ tauT,
    double* __restrict__ pv_all, double* __restrict__ wb_all,
    int* __restrict__ bars) {
  __shared__ __attribute__((aligned(16))) double rb[3][N_];  // v_prev / v_cur(=r1) / r2
  __shared__ __attribute__((aligned(16))) double wwb[2][N_]; // w parity: prev / cur
  __shared__ double red[32];
  __shared__ double nx0s;         // next step's x0 (r2[k+2] after update)
  int blk = blockIdx.x;
  int b = blk % B_;          // batch: clusters each batch's blocks on 2 XCDs
  int t = blk / B_;          // 0..NB_-1
  double* A  = Aall + (size_t)b*N_*N_;
  double* dv = dT   + (size_t)b*N_;
  double* ev = eT   + (size_t)b*N_;
  double* tv = tauT + (size_t)b*N_;
  double* pvB = pv_all + (size_t)b*2*N_;
  double* wbB = wb_all + (size_t)b*2*N_;
  int* bar = bars + b*NBAR_;
  int tid = threadIdx.x, lane = tid & 63, wv = tid >> 6;

  // ---- prologue: r1 <- row 0, r2 <- row 1, zero prev-v/prev-w, sigma_0 ----
  double sig;
  {
    double ps = 0.0;
    if (tid == 0) nx0s = A[1];    // x0 for step 0 (ordered by reduce's barrier)
    for (int j = tid; j < N_; j += 512) {
      rb[0][j] = 0.0;             // v_prev for step 0
      wwb[1][j] = 0.0;            // w_prev for step 0
      double a0 = A[j];
      rb[1][j] = a0;
      rb[2][j] = A[(size_t)N_ + j];
      if (j >= 1) ps += a0 * a0;
    }
    sig = blockReduceD(ps, red);
  }

  for (int k = 0; k < N_ - 2; k++) {
    int rot = k % 3;
    double* vp = rb[rot];             // v_{k-1}
    double* vc = rb[(rot + 1) % 3];   // r1 = row k (state k-1); becomes v_k
    double* r2 = rb[(rot + 2) % 3];   // row k+1 (state k-1)
    double* wp = wwb[(k & 1) ^ 1];    // w_{k-1}
    double* wc = wwb[k & 1];          // w_k
    double* wbk = wbB + (size_t)(k & 1) * N_;
    double* pvk = pvB + (size_t)(k & 1) * N_;

    // ---- phase A: Householder scalars, local & identical per block ----
    double sigma = sig;
    double x0 = nx0s;                 // no thread reads vc[k+1] -> no pre-write barrier
    double alpha, tauk;
    if (sigma == 0.0) { alpha = 0.0; tauk = 0.0; }
    else {
      alpha = (x0 >= 0.0) ? -sqrt(sigma) : sqrt(sigma);
      tauk = 1.0 / (sigma - alpha * x0);
    }
    if (tid == 0) {
      vc[k + 1] = x0 - alpha;
      if (t == 0) { dv[k] = vc[k]; ev[k] = alpha; tv[k] = tauk; }
    }
    __syncthreads();

    // ---- phase B: fused (prev rank-2) + (matvec with v_k), double2; pv publish ----
    int rr = (k + 1) % NB_;
    int rofs = t - rr; if (rofs < 0) rofs += NB_;
    for (int r = (k + 1) + rofs + wv * NB_; r < N_; r += 8 * NB_) {
      double* Ar = A + (size_t)r * N_;
      double vrp = vp[r], wrp = wp[r];
      double pd = 0.0;
      int jbeg = k + 1;
      if (jbeg & 1) {                 // scalar peel to 16B-align the vector loop
        if (lane == 0) {
          double nv = Ar[jbeg] - vrp * wp[jbeg] - wrp * vp[jbeg];
          Ar[jbeg] = nv;
          pd += nv * vc[jbeg];        // j = k+1: never published to pv
        }
        jbeg++;
      }
      if (r == k + 2) {
        for (int j = jbeg + 2 * lane; j < N_; j += 128) {
          double2 av  = *(const double2*)(Ar + j);
          double2 wpv = *(const double2*)(wp + j);
          double2 vpv = *(const double2*)(vp + j);
          double2 vcv = *(const double2*)(vc + j);
          double nv0 = av.x - vrp * wpv.x - wrp * vpv.x;
          double nv1 = av.y - vrp * wpv.y - wrp * vpv.y;
          double2 st; st.x = nv0; st.y = nv1;
          *(double2*)(Ar + j) = st;
          pd += nv0 * vcv.x + nv1 * vcv.y;
          if (j > k + 1) cstore(&pvk[j], nv0);
          cstore(&pvk[j + 1], nv1);   // j+1 >= k+2 always
        }
      } else {
        for (int j = jbeg + 2 * lane; j < N_; j += 128) {
          double2 av  = *(const double2*)(Ar + j);
          double2 wpv = *(const double2*)(wp + j);
          double2 vpv = *(const double2*)(vp + j);
          double2 vcv = *(const double2*)(vc + j);
          double nv0 = av.x - vrp * wpv.x - wrp * vpv.x;
          double nv1 = av.y - vrp * wpv.y - wrp * vpv.y;
          double2 st; st.x = nv0; st.y = nv1;
          *(double2*)(Ar + j) = st;
          pd += nv0 * vcv.x + nv1 * vcv.y;
        }
      }
      for (int o = 32; o > 0; o >>= 1) pd += __shfl_down(pd, o);
      if (lane == 0) cstore(&wbk[r], tauk * pd);
    }
    gbar(bar, k, tid);                // the ONE global sync of the step

    // ---- phase D: issue cloads, archive reflector under their latency, ----
    // ---- ONE reduce, local K/sigma, update replicas ----
    int i0 = k + 1 + tid;
    bool s0 = (i0 < N_), s1 = (i0 + 512 < N_);
    double w0 = s0 ? cload(&wbk[i0]) : 0.0;
    double w1 = s1 ? cload(&wbk[i0 + 512]) : 0.0;
    double p0 = (s0 && tid > 0) ? cload(&pvk[i0]) : 0.0;
    double p1 = s1 ? cload(&pvk[i0 + 512]) : 0.0;
    double wr1 = cload(&wbk[k + 1]);        // broadcast scalars (parallel RTT)
    double wr2 = cload(&wbk[k + 2]);
    // archive reflector over A row k (row k never read again in this kernel;
    // vc array stays intact until next step's phase D, which is past a gbar)
    if ((k % NB_) == t)
      for (int j = k + 1 + tid; j < N_; j += 512) A[(size_t)k * N_ + j] = vc[j];
    double vc0 = s0 ? vc[i0] : 0.0;
    double vc1 = s1 ? vc[i0 + 512] : 0.0;
    double vk1 = vc[k + 1], vk2 = vc[k + 2];
    double r20 = s0 ? r2[i0] : 0.0;
    double r21 = s1 ? r2[i0 + 512] : 0.0;
    double a0v = r20 - vk1 * w0 - wr1 * vc0;
    double a1v = r21 - vk1 * w1 - wr1 * vc1;
    double kd = w0 * vc0 + w1 * vc1;        // j >= k+1
    double sa2 = 0.0, sav = 0.0, sv2 = 0.0; // j >= k+2
    if (s0 && tid > 0) { sa2 += a0v*a0v; sav += a0v*vc0; sv2 += vc0*vc0; }
    if (s1)            { sa2 += a1v*a1v; sav += a1v*vc1; sv2 += vc1*vc1; }
    blockReduce4(kd, sa2, sav, sv2, red);
    double K = 0.5 * tauk * kd;
    double c = 2.0 * K * vk1;
    sig = sa2 + 2.0 * c * sav + c * c * sv2;   // sigma_{k+1}, local scalar
    double wk2 = wr2 - K * vk2;
    if (s0) {
      double wcj = w0 - K * vc0;
      wc[i0] = wcj;
      double nr1v = a0v + c * vc0;             // nr1
      r2[i0] = nr1v;
      if (tid == 1) nx0s = nr1v;               // next step's x0 = r2'[k+2]
      if (tid > 0) vp[i0] = p0 - vk2 * wcj - wk2 * vc0;   // next r2 (row k+2)
    }
    if (s1) {
      double wcj = w1 - K * vc1;
      wc[i0 + 512] = wcj;
      r2[i0 + 512] = a1v + c * vc1;
      vp[i0 + 512] = p1 - vk2 * wcj - wk2 * vc1;
    }
    __syncthreads();
  }

  // ---- epilogue: final d/e from the local replicas (globals are stale) ----
  if (t == 0 && tid == 0) {
    double* r1f = rb[((N_ - 3) + 2) % 3];  // row N-2, final state
    double* r2f = rb[(N_ - 3) % 3];        // row N-1, final state
    dv[N_-2] = r1f[N_-2];
    ev[N_-2] = r1f[N_-1];
    dv[N_-1] = r2f[N_-1];
    ev[N_-1] = 0.0; tv[N_-2] = 0.0; tv[N_-1] = 0.0;
  }
}

// -------- K6: top-48 eigenvalues, 64-point multisection, one wave per (b, j) --------
__global__ __launch_bounds__(64) void k_eigvals_ms(const double* __restrict__ dT,
    const double* __restrict__ eT, double* __restrict__ eval) {
  __shared__ double sd[N_], se[N_];
  int blk = blockIdx.x; int b = blk / G_, j = blk % G_;
  for (int i = threadIdx.x; i < N_; i += 64) {
    sd[i] = dT[(size_t)b*N_ + i];
    se[i] = eT[(size_t)b*N_ + i];
  }
  __syncthreads();
  int lane = threadIdx.x;
  double lo = 1e300, hi = -1e300;
  for (int i = lane; i < N_; i += 64) {
    double r = ((i > 0) ? fabs(se[i-1]) : 0.0) + ((i < N_-1) ? fabs(se[i]) : 0.0);
    lo = fmin(lo, sd[i] - r); hi = fmax(hi, sd[i] + r);
  }
  for (int o = 32; o > 0; o >>= 1) {
    lo = fmin(lo, __shfl_xor(lo, o));
    hi = fmax(hi, __shfl_xor(hi, o));
  }
  double span = hi - lo + 1e-30;
  lo -= span * 1e-6; hi += span * 1e-6;
  int target = N_ - 1 - j;  // ascending index of j-th largest
  const double PIV = 1e-280;
  for (int round = 0; round < 11; round++) {
    double width = hi - lo;
    double mid = lo + width * ((double)(lane + 1) / 65.0);
    int cnt = 0;
    double q = sd[0] - mid;
    if (q <= PIV) { cnt++; q = fmin(q, -PIV); }
    for (int i = 1; i < N_; i++) {
      q = (sd[i] - mid) - se[i-1]*se[i-1] / q;
      if (q <= PIV) { cnt++; q = fmin(q, -PIV); }
    }
    unsigned long long mask = __ballot(cnt > target);
    double nlo, nhi;
    if (mask == 0ULL) { nlo = lo + width * (64.0 / 65.0); nhi = hi; }
    else {
      int m = __ffsll(mask) - 1;
      nhi = lo + width * ((double)(m + 1) / 65.0);
      nlo = (m == 0) ? lo : lo + width * ((double)m / 65.0);
    }
    lo = nlo; hi = nhi;
  }
  if (lane == 0) eval[(size_t)b*G_ + j] = 0.5 * (lo + hi);
}

// -------- K7: inverse iteration (lane per eigenvector) + rare cluster re-orth --------
// THIS ROUND: forward-elimination rewritten with REGISTER CARRY — iteration k's
// input yv[k] equals iteration k-1's yk1 (carried in a register), and the read
// of yv[k+1] is untouched original data (off the dependency chain). Removes the
// per-step global store-to-load round trip (~300cy x 575 x 3 iters). Arithmetic
// sequence is BIT-IDENTICAL to the previous version.
__global__ void k_eigvecs(const double* __restrict__ dT, const double* __restrict__ eT,
    const double* __restrict__ eval,
    double* __restrict__ Ud, double* __restrict__ U1, double* __restrict__ U2,
    double* __restrict__ Um, int* __restrict__ Ufl, double* __restrict__ Yv,
    double* __restrict__ Z) {
  __shared__ double sd[N_], se[N_];
  __shared__ double red0;
  __shared__ int cstart[G_];
  __shared__ double sh_ev[G_];
  int b = blockIdx.x;
  for (int i = threadIdx.x; i < N_; i += blockDim.x) {
    sd[i] = dT[(size_t)b*N_ + i]; se[i] = eT[(size_t)b*N_ + i];
  }
  if (threadIdx.x < G_) sh_ev[threadIdx.x] = eval[(size_t)b*G_ + threadIdx.x];
  __syncthreads();
  int j = threadIdx.x;
  size_t sbase = (size_t)b * N_ * G_;
  double* ud = Ud + sbase; double* u1 = U1 + sbase; double* u2 = U2 + sbase;
  double* um = Um + sbase; int* ufl = Ufl + sbase; double* yv = Yv + sbase;
  if (j < G_) {
    double lam = sh_ev[j];
    double GU = 1e-30 * (1.0 + fabs(lam));
    double ak = sd[0] - lam;
    double bk = se[0];
    for (int k = 0; k < N_ - 1; k++) {
      double sub = se[k];
      double diag1 = sd[k+1] - lam;
      double sup1 = (k < N_ - 2) ? se[k+1] : 0.0;
      double udv, u1v, u2v, umv; int flv;
      if (fabs(ak) >= fabs(sub)) {
        double piv = ak;
        if (fabs(piv) < GU) piv = (piv >= 0.0) ? GU : -GU;
        double ml = sub / piv;
        udv = piv; u1v = bk; u2v = 0.0; umv = ml; flv = 0;
        ak = diag1 - ml * bk; bk = sup1;
      } else {
        double ml = ak / sub;
        udv = sub; u1v = diag1; u2v = sup1; umv = ml; flv = 1;
        ak = bk - ml * diag1; bk = -ml * sup1;
      }
      ud[(size_t)k*G_+j] = udv; u1[(size_t)k*G_+j] = u1v; u2[(size_t)k*G_+j] = u2v;
      um[(size_t)k*G_+j] = umv; ufl[(size_t)k*G_+j] = flv;
    }
    { double piv = ak; if (fabs(piv) < GU) piv = (piv >= 0.0) ? GU : -GU;
      ud[(size_t)(N_-1)*G_+j] = piv; u1[(size_t)(N_-1)*G_+j] = 0.0; u2[(size_t)(N_-1)*G_+j] = 0.0; }
    for (int i = 0; i < N_; i++) {
      unsigned s = (unsigned)(i * 2654435761u) ^ (unsigned)((j + 1) * 40503u) ^ (unsigned)(b * 2246822519u);
      s = s * 1664525u + 1013904223u;
      s ^= s >> 16; s = s * 2246822519u;
      double rv = ((double)(s >> 8) * (1.0 / 16777216.0)) * 2.0 - 1.0;
      if (fabs(rv) < 1e-3) rv = 0.5;
      yv[(size_t)i*G_+j] = rv;
    }
    for (int it = 0; it < 3; it++) {
      if (it) {
        double mx = 0.0;
        for (int i = 0; i < N_; i++) mx = fmax(mx, fabs(yv[(size_t)i*G_+j]));
        double sc = 1.0 / fmax(mx, 1e-300);
        for (int i = 0; i < N_; i++) yv[(size_t)i*G_+j] *= sc;
      }
      // forward elimination, register-carried (bit-identical sequence)
      double ykc = yv[0*G_ + j];
      for (int k = 0; k < N_ - 1; k++) {
        double ynx = yv[(size_t)(k+1)*G_+j];   // original value, not on the chain
        double yk = ykc, yk1 = ynx;
        if (ufl[(size_t)k*G_+j]) { yk = ynx; yk1 = ykc; }
        yk1 -= um[(size_t)k*G_+j] * yk;
        yv[(size_t)k*G_+j] = yk;               // final value for row k
        ykc = yk1;                             // becomes next iteration's yk
      }
      // back substitution (y1/y2 already register-carried)
      double y1, y2 = 0.0;
      { double tt = ykc / ud[(size_t)(N_-1)*G_+j];
        yv[(size_t)(N_-1)*G_+j] = tt; y1 = tt; }
      for (int k = N_ - 2; k >= 0; k--) {
        double tt = yv[(size_t)k*G_+j] - u1[(size_t)k*G_+j]*y1 - u2[(size_t)k*G_+j]*y2;
        tt /= ud[(size_t)k*G_+j];
        yv[(size_t)k*G_+j] = tt;
        y2 = y1; y1 = tt;
      }
    }
    double s2 = 0.0;
    for (int i = 0; i < N_; i++) { double tt = yv[(size_t)i*G_+j]; s2 += tt * tt; }
    double inv = 1.0 / sqrt(fmax(s2, 1e-300));
    double* Zj = Z + ((size_t)b*G_ + j) * N_;
    for (int i = 0; i < N_; i++) Zj[i] = yv[(size_t)i*G_+j] * inv;
  }
  __syncthreads();
  if (threadIdx.x == 0) {
    double tol = 1e-10 * (fabs(sh_ev[0]) + 1.0);
    cstart[0] = 0;
    for (int q = 1; q < G_; q++)
      cstart[q] = ((sh_ev[q-1] - sh_ev[q]) < tol) ? cstart[q-1] : q;
  }
  __syncthreads();
  for (int q = 1; q < G_; q++) {
    if (cstart[q] == q) continue;
    double* Zq = Z + ((size_t)b*G_ + q) * N_;
    for (int p = cstart[q]; p < q; p++) {
      double* Zp = Z + ((size_t)b*G_ + p) * N_;
      double dp = 0.0;
      for (int i = threadIdx.x; i < N_; i += blockDim.x) dp += Zq[i] * Zp[i];
      for (int o = 32; o > 0; o >>= 1) dp += __shfl_down(dp, o);
      if (threadIdx.x == 0) red0 = dp;
      __syncthreads();
      double dd = red0;
      for (int i = threadIdx.x; i < N_; i += blockDim.x) Zq[i] -= dd * Zp[i];
      __syncthreads();
    }
    double s2 = 0.0;
    for (int i = threadIdx.x; i < N_; i += blockDim.x) { double tt = Zq[i]; s2 += tt * tt; }
    for (int o = 32; o > 0; o >>= 1) s2 += __shfl_down(s2, o);
    if (threadIdx.x == 0) red0 = s2;
    __syncthreads();
    double inv = 1.0 / sqrt(fmax(red0, 1e-300));
    for (int i = threadIdx.x; i < N_; i += blockDim.x) Zq[i] *= inv;
    __syncthreads();
  }
}

// -------- K8: back-transform, one wave per (batch, eigenvector), Z in registers --------
__global__ __launch_bounds__(64) void k_backxf_mb(const double* __restrict__ Aall,
    const double* __restrict__ tauT, double* __restrict__ Z) {
  int blk = blockIdx.x;
  int b = blk / G_, q = blk % G_;
  const double* A = Aall + (size_t)b*N_*N_;
  const double* tau = tauT + (size_t)b*N_;
  double* Zq = Z + ((size_t)b*G_ + q) * N_;
  int lane = threadIdx.x;
  double z[9];
#pragma unroll
  for (int m = 0; m < 9; m++) z[m] = Zq[lane + 64*m];
  for (int k = N_ - 3; k >= 0; k--) {
    double t = tau[k];
    if (t == 0.0) continue;
    const double* vk = A + (size_t)k*N_;
    double vv[9]; double p = 0.0;
#pragma unroll
    for (int m = 0; m < 9; m++) {
      int i = lane + 64*m;
      double vi = (i > k) ? vk[i] : 0.0;
      vv[m] = vi; p += vi * z[m];
    }
    for (int o = 32; o > 0; o >>= 1) p += __shfl_down(p, o);
    p = __shfl(p, 0);
    double s = t * p;
#pragma unroll
    for (int m = 0; m < 9; m++) z[m] -= s * vv[m];
  }
#pragma unroll
  for (int m = 0; m < 9; m++) Zq[lane + 64*m] = z[m];
}

// -------- K9: belong = argmax_q |V[n][q]| (first max) --------
__global__ void k_belong(const double* __restrict__ Z, int* __restrict__ belong) {
  int idx = blockIdx.x * blockDim.x + threadIdx.x;
  if (idx >= B_ * N_) return;
  int b = idx / N_, n = idx % N_;
  const double* Zb = Z + (size_t)b*G_*N_;
  double best = -1.0; int bi = 0;
  for (int q = 0; q < G_; q++) {
    double av = fabs(Zb[(size_t)q*N_ + n]);
    if (av > best) { best = av; bi = q; }
  }
  belong[idx] = bi;
}

// -------- K10: NMS + quota scheduling + index emission (one block per batch) --------
__global__ __launch_bounds__(256) void k_nms(const float* __restrict__ sim,
    const float* __restrict__ cls, const int* __restrict__ belong,
    const float* __restrict__ thrF, float* __restrict__ outF) {
  __shared__ float nsv[N_], rsv[N_];
  __shared__ int bl_s[N_];
  __shared__ int lists[N_];
  __shared__ int off[G_ + 1];
  __shared__ int kc[G_], gc[G_], lowv[G_], upv[G_], tokd[G_], sortg[G_], pre[G_ + 1];
  __shared__ int gathered[L_];
  __shared__ int anyv;
  __shared__ float shthr;
  int b = blockIdx.x, tid = threadIdx.x;
  const float* simb = sim + (size_t)b*N_*N_;
  if (tid == 0) shthr = thrF[b];
  if (tid < G_) gc[tid] = 0;
  __syncthreads();
  for (int i = tid; i < N_; i += 256) {
    int g = belong[b*N_ + i];
    bl_s[i] = g;
    float sc = cls[b*N_ + i];
    nsv[i] = sc; rsv[i] = sc;
    atomicAdd(&gc[g], 1);
  }
  __syncthreads();
  if (tid == 0) {           // deterministic (ascending-n) group list build
    off[0] = 0;
    for (int g = 0; g < G_; g++) off[g+1] = off[g] + gc[g];
    for (int g = 0; g < G_; g++) pre[g] = off[g];
    for (int n = 0; n < N_; n++) lists[pre[bl_s[n]]++] = n;
  }
  __syncthreads();
  float thr = shthr;
  float gs = 1000.0f;
  int myc = 0;
  for (int iter = 0; iter < N_ + 8; iter++) {
    if (tid == 0) anyv = 0;
    __syncthreads();
    int m = -1;
    if (tid < G_) {
      float mx = 0.0f;
      for (int a = off[tid]; a < off[tid+1]; a++) {
        int n2 = lists[a];
        float vv = nsv[n2];
        if (vv > mx) { mx = vv; m = n2; }
      }
      if (m >= 0) anyv = 1;
    }
    __syncthreads();
    if (m >= 0) {
      rsv[m] = gs;
      nsv[m] = 0.0f;
      const float* srow = simb + (size_t)m*N_;
      for (int a = off[tid]; a < off[tid+1]; a++) {
        int n2 = lists[a];
        if (nsv[n2] > 0.0f && srow[n2] > thr) nsv[n2] = 0.0f;
      }
      myc++;
    }
    gs -= 1.0f;
    __syncthreads();
    if (!anyv) break;
  }
  if (tid < G_) kc[tid] = myc;
  __syncthreads();
  if (tid == 0) {
    int sumkc = 0; for (int g = 0; g < G_; g++) sumkc += kc[g];
    int sumlow = 0;
    for (int g = 0; g < G_; g++) {
      lowv[g] = (gc[g] < 1) ? gc[g] : 1;
      int u = 15; if (gc[g] < u) u = gc[g]; if (kc[g] < u) u = kc[g];
      upv[g] = u; sumlow += lowv[g];
    }
    int su = 0; for (int g = 0; g < G_; g++) su += upv[g];
    while (su < NEED_) {
      su = 0;
      for (int g = 0; g < G_; g++) { int u = upv[g] + 1; if (u > gc[g]) u = gc[g]; upv[g] = u; su += u; }
    }
    int other = NEED_ - sumlow - 1; if (other < 0) other = 0;
    float s = (float)sumkc;
    float c = 0.0f; int prevR = 0;
    float otherf = (float)other;
    for (int g = 0; g < G_; g++) {
      float nc = (float)kc[g] / s;
      c += nc;
      int R = (int)rintf(c * otherf);          // round half-to-even like jnp.round
      int od = R - prevR; prevR = R;
      int t0 = od + lowv[g]; if (t0 > upv[g]) t0 = upv[g];
      tokd[g] = t0;
    }
    for (int g = 0; g < G_; g++) sortg[g] = g;
    for (int a = 1; a < G_; a++) {            // stable insertion sort, kc descending
      int vIdx = sortg[a]; int key = kc[vIdx]; int p2 = a - 1;
      while (p2 >= 0 && kc[sortg[p2]] < key) { sortg[p2+1] = sortg[p2]; p2--; }
      sortg[p2+1] = vIdx;
    }
    int target = other + sumlow;
    int sumd = 0; for (int g = 0; g < G_; g++) sumd += tokd[g];
    int fg = 0;
    while (sumd < target) {
      int gi = sortg[(fg < G_-1) ? fg : (G_-1)];
      int fill = upv[gi] - tokd[gi];
      int rem = target - sumd;
      if (rem < fill) fill = rem;
      tokd[gi] += fill; sumd += fill;
      fg++;
      if (fg > 100000) break;
    }
    pre[0] = 0; for (int g = 0; g < G_; g++) pre[g+1] = pre[g] + tokd[g];
  }
  __syncthreads();
  for (int i = tid; i < L_; i += 256) gathered[i] = 0;
  __syncthreads();
  if (tid < G_) {
    int g = tid;
    int td = tokd[g], base = pre[g];
    for (int t = 0; t < td; t++) {
      float bv = -3e38f; int bn2 = 0;
      for (int a = off[g]; a < off[g+1]; a++) {
        int n2 = lists[a];
        float vv = rsv[n2];
        if (vv > bv) { bv = vv; bn2 = n2; }
      }
      rsv[bn2] = -3e38f;
      int pos = base + t;
      if (pos < L_) gathered[pos] = bn2;
    }
  }
  __syncthreads();
  if (tid < NEED_) {
    float val = (tid == 0) ? 0.0f : (float)(gathered[tid - 1] + 1);
    outF[(size_t)B_*NEED_*D_ + (size_t)b*NEED_ + tid] = val;
  }
}

// -------- K11: gather selected hidden rows --------
__global__ void k_gather(const float* __restrict__ hs, float* __restrict__ outF) {
  int blk = blockIdx.x;
  int b = blk / NEED_, i = blk % NEED_;
  int idx = (int)outF[(size_t)B_*NEED_*D_ + (size_t)b*NEED_ + i];
  const float4* src = (const float4*)(hs + ((size_t)b*T_ + idx) * (size_t)D_);
  float4* dst = (float4*)(outF + ((size_t)b*NEED_ + i) * (size_t)D_);
  dst[threadIdx.x] = src[threadIdx.x];
}

extern "C" void kernel_launch(void* const* d_in, const int* in_sizes, int n_in,
                              void* d_out, int out_size, void* d_ws, size_t ws_size,
                              hipStream_t stream) {
  if (ws_size < WS_NEEDED) return;
  const float* hs   = (const float*)d_in[0];
  const float* attn = (const float*)d_in[1];
  float* outF = (float*)d_out;
  char* w = (char*)d_ws;
  float*  msig = (float*)(w + OF_MSIG);
  float*  sim  = (float*)(w + OF_SIM);
  double* A    = (double*)(w + OF_A);
  double* ms   = (double*)(w + OF_MS);
  double* invn = (double*)(w + OF_INVN);
  float*  cls  = (float*)(w + OF_CLS);
  double* dT   = (double*)(w + OF_DT);
  double* eT   = (double*)(w + OF_ET);
  double* tauT = (double*)(w + OF_TAU);
  double* eval = (double*)(w + OF_EVAL);
  double* Z    = (double*)(w + OF_Z);
  double* part = (double*)(w + OF_PART);
  float*  thrF = (float*)(w + OF_THR);
  int*    belong = (int*)(w + OF_BEL);
  int*    bars = (int*)(w + OF_BAR);
  double* wb   = (double*)(w + OF_WB);
  double* pv   = (double*)(w + OF_PV_ALIAS);   // dead msig region during tridiag
  // inverse-iteration scratch aliases msig region (msig dead after the Gram GEMM)
  double* Ud = (double*)(w + OF_MSIG);
  double* U1 = Ud + (size_t)B_*N_*G_;
  double* U2 = U1 + (size_t)B_*N_*G_;
  double* Um = U2 + (size_t)B_*N_*G_;
  double* Yv = Um + (size_t)B_*N_*G_;
  int*    Ufl = (int*)(Yv + (size_t)B_*N_*G_);

  k_prep<<<B_*N_, 256, 0, stream>>>(hs, msig, ms, invn, bars);
  k_cls<<<(B_*N_ + 255)/256, 256, 0, stream>>>(attn, cls);
  k_gemm<<<dim3(N_/32, N_/32, B_), 256, 0, stream>>>(hs, msig, ms, invn, A, sim, 0);
  k_gemm<<<dim3(N_/32, N_/32, B_), 256, 0, stream>>>(hs, msig, ms, invn, A, sim, 1);
  k_simsum<<<B_*36, 256, 0, stream>>>(sim, part);
  k_thr<<<1, 64, 0, stream>>>(part, thrF);
  k_tridiag_mb<<<B_*NB_, 512, 0, stream>>>(A, dT, eT, tauT, pv, wb, bars);
  k_eigvals_ms<<<B_*G_, 64, 0, stream>>>(dT, eT, eval);
  k_eigvecs<<<B_, 64, 0, stream>>>(dT, eT, eval, Ud, U1, U2, Um, Ufl, Yv, Z);
  k_backxf_mb<<<B_*G_, 64, 0, stream>>>(A, tauT, Z);
  k_belong<<<(B_*N_ + 255)/256, 256, 0, stream>>>(Z, belong);
  k_nms<<<B_, 256, 0, stream>>>(sim, cls, belong, thrF, outF);
  k_gather<<<B_*NEED_, 256, 0, stream>>>(hs, outF);
}

// Round 7
// 7352.319 us; speedup vs baseline: 1.0378x; 1.0378x over previous
//
#include <hip/hip_runtime.h>
#include <math.h>

// Problem constants
constexpr int B_ = 4, T_ = 577, N_ = 576, D_ = 1024, G_ = 48, H_ = 16;
constexpr int NEED_ = 192, L_ = 191;
constexpr int TRIU_CNT = N_ * (N_ - 1) / 2; // 165600
constexpr int NB_ = 8;                      // blocks per batch in tridiag (512 thr each)
constexpr int NBAR_ = 640;                  // barrier slots per batch (1 per step)

// ---------------- workspace layout (bytes) ----------------
constexpr size_t OF_MSIG = 0;                                    // f32 B*N*D (dead after GEMM; aliased: invit scratch @0, pv @8MB)
constexpr size_t OF_SIM  = OF_MSIG + (size_t)B_*N_*D_*4;
constexpr size_t OF_A    = OF_SIM  + (size_t)B_*N_*N_*4;         // f64 Gram (rows also hold archived reflectors)
constexpr size_t OF_MS   = OF_A    + (size_t)B_*N_*N_*8;         // f64 sigmoid row sums
constexpr size_t OF_INVN = OF_MS   + (size_t)B_*N_*8;            // f64 1/norm of raw hs rows
constexpr size_t OF_CLS  = OF_INVN + (size_t)B_*N_*8;            // f32 cls attention sums
constexpr size_t OF_DT   = OF_CLS  + (size_t)B_*N_*4;            // f64 tridiag diagonal
constexpr size_t OF_ET   = OF_DT   + (size_t)B_*N_*8;            // f64 tridiag off-diagonal
constexpr size_t OF_TAU  = OF_ET   + (size_t)B_*N_*8;            // f64 Householder taus
constexpr size_t OF_EVAL = OF_TAU  + (size_t)B_*N_*8;            // f64 top-48 eigenvalues (descending)
constexpr size_t OF_Z    = OF_EVAL + (size_t)B_*G_*8;            // f64 eigenvectors [b][q][i]
constexpr size_t OF_PART = OF_Z    + (size_t)B_*G_*N_*8;         // f64 simmean partials B*36
constexpr size_t OF_THR  = OF_PART + (size_t)B_*36*8;            // f32 thresholds (padded)
constexpr size_t OF_BEL  = OF_THR  + 64;                         // int belong
constexpr size_t OF_BAR  = OF_BEL  + (size_t)B_*N_*4;            // int barrier counters
constexpr size_t OF_FLG  = OF_BAR  + (size_t)B_*NBAR_*4;         // int (legacy, unused)
constexpr size_t OF_VB   = OF_FLG  + (size_t)B_*16*4;            // f64 (legacy, unused)
constexpr size_t OF_WB   = OF_VB   + (size_t)B_*N_*8;            // f64 wbuf ×2 (parity double-buffer)
constexpr size_t OF_SG   = OF_WB   + (size_t)B_*2*N_*8;          // f64 (legacy, unused)
constexpr size_t OF_KP   = OF_SG   + (size_t)B_*8*8;             // f64 (legacy, unused)
constexpr size_t WS_NEEDED = OF_KP + (size_t)B_*2*16*8;

// pv: pivot-row publish buffer, ×2 parity, per batch, in the dead msig region
constexpr size_t OF_PV_ALIAS = OF_MSIG + ((size_t)8 << 20);      // f64 B*2*N

__device__ __forceinline__ double blockReduceD(double x, double* red) {
  int lane = threadIdx.x & 63, wv = threadIdx.x >> 6;
  int nw = (blockDim.x + 63) >> 6;
  for (int o = 32; o > 0; o >>= 1) x += __shfl_down(x, o);
  __syncthreads();                // protect red from previous use
  if (lane == 0) red[wv] = x;
  __syncthreads();
  double t = red[0];
  for (int i = 1; i < nw; i++) t += red[i];
  return t;                       // same deterministic value on all threads/blocks
}

// 4-value block reduction in one LDS round (deterministic, identical per block)
__device__ __forceinline__ void blockReduce4(double& x0, double& x1, double& x2,
                                             double& x3, double* red) {
  int lane = threadIdx.x & 63, wv = threadIdx.x >> 6;
  int nw = (blockDim.x + 63) >> 6;
  for (int o = 32; o > 0; o >>= 1) {
    x0 += __shfl_down(x0, o); x1 += __shfl_down(x1, o);
    x2 += __shfl_down(x2, o); x3 += __shfl_down(x3, o);
  }
  __syncthreads();
  if (lane == 0) { red[wv*4+0]=x0; red[wv*4+1]=x1; red[wv*4+2]=x2; red[wv*4+3]=x3; }
  __syncthreads();
  double t0 = red[0], t1 = red[1], t2 = red[2], t3 = red[3];
  for (int i = 1; i < nw; i++) {
    t0 += red[i*4+0]; t1 += red[i*4+1]; t2 += red[i*4+2]; t3 += red[i*4+3];
  }
  x0 = t0; x1 = t1; x2 = t2; x3 = t3;
}

// coherent (agent-scope, cache-bypassing) load/store for cross-block data
__device__ __forceinline__ double cload(const double* p) {
  return __hip_atomic_load(p, __ATOMIC_RELAXED, __HIP_MEMORY_SCOPE_AGENT);
}
__device__ __forceinline__ void cstore(double* p, double x) {
  __hip_atomic_store(p, x, __ATOMIC_RELAXED, __HIP_MEMORY_SCOPE_AGENT);
}

// device barrier among the NB_ blocks of one batch (R1/R3-measured design).
__device__ __forceinline__ void gbar(int* bar, int slot, int tid) {
  __syncthreads();
  if (tid == 0) {
    __hip_atomic_fetch_add(&bar[slot], 1, __ATOMIC_RELAXED, __HIP_MEMORY_SCOPE_AGENT);
    while (__hip_atomic_load(&bar[slot], __ATOMIC_ACQUIRE, __HIP_MEMORY_SCOPE_AGENT) < NB_)
      __builtin_amdgcn_s_sleep(2);
  }
  __syncthreads();
  __asm__ volatile("" ::: "memory");
}

// -------- K1: sigmoid features, row sums, inverse norms (+ zero barrier slots) --------
__global__ void k_prep(const float* __restrict__ hs, float* __restrict__ msig,
                       double* __restrict__ ms, double* __restrict__ invn,
                       int* __restrict__ bars) {
  __shared__ double red[16];
  if (blockIdx.x == 0) {
    for (int i = threadIdx.x; i < B_ * NBAR_; i += blockDim.x) bars[i] = 0;
  }
  int bn = blockIdx.x; int b = bn / N_, n = bn % N_;
  const float* row = hs + ((size_t)b*T_ + (n+1)) * (size_t)D_;
  float* mrow = msig + (size_t)bn * D_;
  double ssig = 0.0, ssq = 0.0;
  for (int d = threadIdx.x; d < D_; d += blockDim.x) {
    float x = row[d];
    float sg = 1.0f / (1.0f + expf(-x));
    mrow[d] = sg;
    ssig += (double)sg;
    ssq  += (double)x * (double)x;
  }
  double tot_sig = blockReduceD(ssig, red);
  double tot_sq  = blockReduceD(ssq, red);
  if (threadIdx.x == 0) {
    ms[bn] = tot_sig;
    invn[bn] = 1.0 / fmax(sqrt(tot_sq), 1e-12);
  }
}

// -------- K2: cls attention sums --------
__global__ void k_cls(const float* __restrict__ attn, float* __restrict__ cls) {
  int idx = blockIdx.x * blockDim.x + threadIdx.x;
  if (idx >= B_ * N_) return;
  int b = idx / N_, n = idx % N_;
  float s = 0.0f;
  for (int h = 0; h < H_; h++)
    s += attn[(((size_t)b*H_ + h) * T_ + 0) * T_ + (1 + n)];
  cls[idx] = s;
}

// -------- K3: tiled X*X^T GEMM; mode0 -> Gram (f64), mode1 -> cosine sim (f32) --------
__global__ void k_gemm(const float* __restrict__ hs, const float* __restrict__ msig,
                       const double* __restrict__ ms, const double* __restrict__ invn,
                       double* __restrict__ Aout, float* __restrict__ sim, int mode) {
  __shared__ float As[32][17], Bs[32][17];
  int b = blockIdx.z;
  int bi0 = blockIdx.y * 32, bj0 = blockIdx.x * 32;
  const float* base = (mode == 0) ? (msig + (size_t)b*N_*D_)
                                  : (hs + ((size_t)b*T_ + 1) * (size_t)D_);
  int tid = threadIdx.x;
  int tx = tid & 15, ty = tid >> 4;
  double a00 = 0, a01 = 0, a10 = 0, a11 = 0;
  for (int k0 = 0; k0 < D_; k0 += 16) {
    int r = tid >> 4, c = tid & 15;
    As[r][c] = base[(size_t)(bi0 + r) * D_ + k0 + c];
    Bs[r][c] = base[(size_t)(bj0 + r) * D_ + k0 + c];
    int e = tid + 256; r = e >> 4; c = e & 15;
    As[r][c] = base[(size_t)(bi0 + r) * D_ + k0 + c];
    Bs[r][c] = base[(size_t)(bj0 + r) * D_ + k0 + c];
    __syncthreads();
#pragma unroll
    for (int kk = 0; kk < 16; kk++) {
      double x0 = As[2*ty][kk],   x1 = As[2*ty+1][kk];
      double y0 = Bs[2*tx][kk],   y1 = Bs[2*tx+1][kk];
      a00 += x0*y0; a01 += x0*y1; a10 += x1*y0; a11 += x1*y1;
    }
    __syncthreads();
  }
  int i0 = bi0 + 2*ty, j0 = bj0 + 2*tx;
  if (mode == 0) {
    const double* msb = ms + (size_t)b*N_;
    double* Ab = Aout + (size_t)b*N_*N_;
    const double inv1024 = 1.0 / 1024.0;
    Ab[(size_t)i0*N_ + j0]         = a00 - msb[i0]*msb[j0]*inv1024;
    Ab[(size_t)i0*N_ + j0+1]       = a01 - msb[i0]*msb[j0+1]*inv1024;
    Ab[(size_t)(i0+1)*N_ + j0]     = a10 - msb[i0+1]*msb[j0]*inv1024;
    Ab[(size_t)(i0+1)*N_ + j0+1]   = a11 - msb[i0+1]*msb[j0+1]*inv1024;
  } else {
    const double* iv = invn + (size_t)b*N_;
    float* sb = sim + (size_t)b*N_*N_;
    sb[(size_t)i0*N_ + j0]       = (float)(a00 * iv[i0]*iv[j0]);
    sb[(size_t)i0*N_ + j0+1]     = (float)(a01 * iv[i0]*iv[j0+1]);
    sb[(size_t)(i0+1)*N_ + j0]   = (float)(a10 * iv[i0+1]*iv[j0]);
    sb[(size_t)(i0+1)*N_ + j0+1] = (float)(a11 * iv[i0+1]*iv[j0+1]);
  }
}

// -------- K4: upper-triangle sum partials --------
__global__ void k_simsum(const float* __restrict__ sim, double* __restrict__ part) {
  __shared__ double red[4];
  int blk = blockIdx.x; int b = blk / 36, s = blk % 36;
  const float* sb = sim + (size_t)b*N_*N_;
  double p = 0.0;
  for (int i = s*16; i < s*16 + 16; i++) {
    const float* row = sb + (size_t)i*N_;
    for (int j = i + 1 + threadIdx.x; j < N_; j += blockDim.x) p += (double)row[j];
  }
  double t = blockReduceD(p, red);
  if (threadIdx.x == 0) part[blk] = t;
}

__global__ void k_thr(const double* __restrict__ part, float* __restrict__ thrF) {
  int b = threadIdx.x;
  if (b < B_) {
    double s = 0.0;
    for (int i = 0; i < 36; i++) s += part[b*36 + i];
    thrF[b] = 6.0f * (float)(s / (double)TRIU_CNT);
  }
}

// -------- K5: multi-block Householder tridiagonalization --------
// R5-verified structure. BYTE-IDENTICAL this round.
__global__ __launch_bounds__(512) void k_tridiag_mb(double* __restrict__ Aall,
    double* __restrict__ dT, double* __restrict__ eT, double* __restrict__ tauT,
    double* __restrict__ pv_all, double* __restrict__ wb_all,
    int* __restrict__ bars) {
  __shared__ __attribute__((aligned(16))) double rb[3][N_];  // v_prev / v_cur(=r1) / r2
  __shared__ __attribute__((aligned(16))) double wwb[2][N_]; // w parity: prev / cur
  __shared__ double red[32];
  __shared__ double nx0s;         // next step's x0 (r2[k+2] after update)
  int blk = blockIdx.x;
  int b = blk % B_;          // batch: clusters each batch's blocks on 2 XCDs
  int t = blk / B_;          // 0..NB_-1
  double* A  = Aall + (size_t)b*N_*N_;
  double* dv = dT   + (size_t)b*N_;
  double* ev = eT   + (size_t)b*N_;
  double* tv = tauT + (size_t)b*N_;
  double* pvB = pv_all + (size_t)b*2*N_;
  double* wbB = wb_all + (size_t)b*2*N_;
  int* bar = bars + b*NBAR_;
  int tid = threadIdx.x, lane = tid & 63, wv = tid >> 6;

  // ---- prologue: r1 <- row 0, r2 <- row 1, zero prev-v/prev-w, sigma_0 ----
  double sig;
  {
    double ps = 0.0;
    if (tid == 0) nx0s = A[1];    // x0 for step 0 (ordered by reduce's barrier)
    for (int j = tid; j < N_; j += 512) {
      rb[0][j] = 0.0;             // v_prev for step 0
      wwb[1][j] = 0.0;            // w_prev for step 0
      double a0 = A[j];
      rb[1][j] = a0;
      rb[2][j] = A[(size_t)N_ + j];
      if (j >= 1) ps += a0 * a0;
    }
    sig = blockReduceD(ps, red);
  }

  for (int k = 0; k < N_ - 2; k++) {
    int rot = k % 3;
    double* vp = rb[rot];             // v_{k-1}
    double* vc = rb[(rot + 1) % 3];   // r1 = row k (state k-1); becomes v_k
    double* r2 = rb[(rot + 2) % 3];   // row k+1 (state k-1)
    double* wp = wwb[(k & 1) ^ 1];    // w_{k-1}
    double* wc = wwb[k & 1];          // w_k
    double* wbk = wbB + (size_t)(k & 1) * N_;
    double* pvk = pvB + (size_t)(k & 1) * N_;

    // ---- phase A: Householder scalars, local & identical per block ----
    double sigma = sig;
    double x0 = nx0s;                 // no thread reads vc[k+1] -> no pre-write barrier
    double alpha, tauk;
    if (sigma == 0.0) { alpha = 0.0; tauk = 0.0; }
    else {
      alpha = (x0 >= 0.0) ? -sqrt(sigma) : sqrt(sigma);
      tauk = 1.0 / (sigma - alpha * x0);
    }
    if (tid == 0) {
      vc[k + 1] = x0 - alpha;
      if (t == 0) { dv[k] = vc[k]; ev[k] = alpha; tv[k] = tauk; }
    }
    __syncthreads();

    // ---- phase B: fused (prev rank-2) + (matvec with v_k), double2; pv publish ----
    int rr = (k + 1) % NB_;
    int rofs = t - rr; if (rofs < 0) rofs += NB_;
    for (int r = (k + 1) + rofs + wv * NB_; r < N_; r += 8 * NB_) {
      double* Ar = A + (size_t)r * N_;
      double vrp = vp[r], wrp = wp[r];
      double pd = 0.0;
      int jbeg = k + 1;
      if (jbeg & 1) {                 // scalar peel to 16B-align the vector loop
        if (lane == 0) {
          double nv = Ar[jbeg] - vrp * wp[jbeg] - wrp * vp[jbeg];
          Ar[jbeg] = nv;
          pd += nv * vc[jbeg];        // j = k+1: never published to pv
        }
        jbeg++;
      }
      if (r == k + 2) {
        for (int j = jbeg + 2 * lane; j < N_; j += 128) {
          double2 av  = *(const double2*)(Ar + j);
          double2 wpv = *(const double2*)(wp + j);
          double2 vpv = *(const double2*)(vp + j);
          double2 vcv = *(const double2*)(vc + j);
          double nv0 = av.x - vrp * wpv.x - wrp * vpv.x;
          double nv1 = av.y - vrp * wpv.y - wrp * vpv.y;
          double2 st; st.x = nv0; st.y = nv1;
          *(double2*)(Ar + j) = st;
          pd += nv0 * vcv.x + nv1 * vcv.y;
          if (j > k + 1) cstore(&pvk[j], nv0);
          cstore(&pvk[j + 1], nv1);   // j+1 >= k+2 always
        }
      } else {
        for (int j = jbeg + 2 * lane; j < N_; j += 128) {
          double2 av  = *(const double2*)(Ar + j);
          double2 wpv = *(const double2*)(wp + j);
          double2 vpv = *(const double2*)(vp + j);
          double2 vcv = *(const double2*)(vc + j);
          double nv0 = av.x - vrp * wpv.x - wrp * vpv.x;
          double nv1 = av.y - vrp * wpv.y - wrp * vpv.y;
          double2 st; st.x = nv0; st.y = nv1;
          *(double2*)(Ar + j) = st;
          pd += nv0 * vcv.x + nv1 * vcv.y;
        }
      }
      for (int o = 32; o > 0; o >>= 1) pd += __shfl_down(pd, o);
      if (lane == 0) cstore(&wbk[r], tauk * pd);
    }
    gbar(bar, k, tid);                // the ONE global sync of the step

    // ---- phase D: issue cloads, archive reflector under their latency, ----
    // ---- ONE reduce, local K/sigma, update replicas ----
    int i0 = k + 1 + tid;
    bool s0 = (i0 < N_), s1 = (i0 + 512 < N_);
    double w0 = s0 ? cload(&wbk[i0]) : 0.0;
    double w1 = s1 ? cload(&wbk[i0 + 512]) : 0.0;
    double p0 = (s0 && tid > 0) ? cload(&pvk[i0]) : 0.0;
    double p1 = s1 ? cload(&pvk[i0 + 512]) : 0.0;
    double wr1 = cload(&wbk[k + 1]);        // broadcast scalars (parallel RTT)
    double wr2 = cload(&wbk[k + 2]);
    // archive reflector over A row k (row k never read again in this kernel;
    // vc array stays intact until next step's phase D, which is past a gbar)
    if ((k % NB_) == t)
      for (int j = k + 1 + tid; j < N_; j += 512) A[(size_t)k * N_ + j] = vc[j];
    double vc0 = s0 ? vc[i0] : 0.0;
    double vc1 = s1 ? vc[i0 + 512] : 0.0;
    double vk1 = vc[k + 1], vk2 = vc[k + 2];
    double r20 = s0 ? r2[i0] : 0.0;
    double r21 = s1 ? r2[i0 + 512] : 0.0;
    double a0v = r20 - vk1 * w0 - wr1 * vc0;
    double a1v = r21 - vk1 * w1 - wr1 * vc1;
    double kd = w0 * vc0 + w1 * vc1;        // j >= k+1
    double sa2 = 0.0, sav = 0.0, sv2 = 0.0; // j >= k+2
    if (s0 && tid > 0) { sa2 += a0v*a0v; sav += a0v*vc0; sv2 += vc0*vc0; }
    if (s1)            { sa2 += a1v*a1v; sav += a1v*vc1; sv2 += vc1*vc1; }
    blockReduce4(kd, sa2, sav, sv2, red);
    double K = 0.5 * tauk * kd;
    double c = 2.0 * K * vk1;
    sig = sa2 + 2.0 * c * sav + c * c * sv2;   // sigma_{k+1}, local scalar
    double wk2 = wr2 - K * vk2;
    if (s0) {
      double wcj = w0 - K * vc0;
      wc[i0] = wcj;
      double nr1v = a0v + c * vc0;             // nr1
      r2[i0] = nr1v;
      if (tid == 1) nx0s = nr1v;               // next step's x0 = r2'[k+2]
      if (tid > 0) vp[i0] = p0 - vk2 * wcj - wk2 * vc0;   // next r2 (row k+2)
    }
    if (s1) {
      double wcj = w1 - K * vc1;
      wc[i0 + 512] = wcj;
      r2[i0 + 512] = a1v + c * vc1;
      vp[i0 + 512] = p1 - vk2 * wcj - wk2 * vc1;
    }
    __syncthreads();
  }

  // ---- epilogue: final d/e from the local replicas (globals are stale) ----
  if (t == 0 && tid == 0) {
    double* r1f = rb[((N_ - 3) + 2) % 3];  // row N-2, final state
    double* r2f = rb[(N_ - 3) % 3];        // row N-1, final state
    dv[N_-2] = r1f[N_-2];
    ev[N_-2] = r1f[N_-1];
    dv[N_-1] = r2f[N_-1];
    ev[N_-1] = 0.0; tv[N_-2] = 0.0; tv[N_-1] = 0.0;
  }
}

// -------- K6: top-48 eigenvalues, 64-point multisection --------
// THIS ROUND: division-free Sturm via the leading-minor recurrence
//   p_i = (d_i - mid) p_{i-1} - e_{i-1}^2 p_{i-2};  count = #sign changes.
// Dependent chain per step is ONE f64 FMA (~10cy) instead of an f64 divide
// (~130cy) -> ~10x shorter serial chain. Overflow guarded by a rescale on
// max(|p|,|p_{i-1}|) every 4 steps (growth per 4 steps <= ~1e16 -> 1e160
// thresholds can never overflow/underflow; zero-safety clamps keep sign
// state). e^2 pre-squared into LDS (bounds use |e| first). Rounds 11 -> 9:
// final width ~ span/65^9 ~ 3e-13, below the f32-SVD reference's own error.
__global__ __launch_bounds__(64) void k_eigvals_ms(const double* __restrict__ dT,
    const double* __restrict__ eT, double* __restrict__ eval) {
  __shared__ double sd[N_], se2[N_];
  int blk = blockIdx.x; int b = blk / G_, j = blk % G_;
  int lane = threadIdx.x;
  for (int i = lane; i < N_; i += 64) {
    sd[i] = dT[(size_t)b*N_ + i];
    se2[i] = eT[(size_t)b*N_ + i];          // raw e for bounds; squared below
  }
  __syncthreads();
  double lo = 1e300, hi = -1e300;
  for (int i = lane; i < N_; i += 64) {
    double r = ((i > 0) ? fabs(se2[i-1]) : 0.0) + ((i < N_-1) ? fabs(se2[i]) : 0.0);
    lo = fmin(lo, sd[i] - r); hi = fmax(hi, sd[i] + r);
  }
  for (int o = 32; o > 0; o >>= 1) {
    lo = fmin(lo, __shfl_xor(lo, o));
    hi = fmax(hi, __shfl_xor(hi, o));
  }
  double span = hi - lo + 1e-30;
  lo -= span * 1e-6; hi += span * 1e-6;
  __syncthreads();
  for (int i = lane; i < N_; i += 64) { double e = se2[i]; se2[i] = e * e; }
  __syncthreads();
  int target = N_ - 1 - j;  // ascending index of j-th largest
  for (int round = 0; round < 9; round++) {
    double width = hi - lo;
    double mid = lo + width * ((double)(lane + 1) / 65.0);
    double pm1 = 1.0;
    double pcur = sd[0] - mid;
    int cnt = (pcur <= 0.0) ? 1 : 0;
    if (pcur == 0.0) pcur = -1e-300;
    for (int i = 1; i < N_; i++) {
      double pnew = (sd[i] - mid) * pcur - se2[i-1] * pm1;
      bool chg = ((pnew < 0.0) != (pcur < 0.0)) || (pnew == 0.0);
      cnt += chg ? 1 : 0;
      if (pnew == 0.0) pnew = (pcur < 0.0) ? 1e-300 : -1e-300; // sign after change
      pm1 = pcur; pcur = pnew;
      if ((i & 3) == 3) {
        double ap = fmax(fabs(pcur), fabs(pm1));
        double s = (ap > 1e160) ? 1e-160 : ((ap < 1e-160) ? 1e160 : 1.0);
        if (s != 1.0) {
          pcur *= s; pm1 *= s;
          if (pcur == 0.0) pcur = (pm1 < 0.0) ? 1e-300 : -1e-300;
          if (pm1 == 0.0)  pm1  = (pcur < 0.0) ? 1e-300 : -1e-300;
        }
      }
    }
    unsigned long long mask = __ballot(cnt > target);
    double nlo, nhi;
    if (mask == 0ULL) { nlo = lo + width * (64.0 / 65.0); nhi = hi; }
    else {
      int m = __ffsll(mask) - 1;
      nhi = lo + width * ((double)(m + 1) / 65.0);
      nlo = (m == 0) ? lo : lo + width * ((double)m / 65.0);
    }
    lo = nlo; hi = nhi;
  }
  if (lane == 0) eval[(size_t)b*G_ + j] = 0.5 * (lo + hi);
}

// -------- K7: inverse iteration (lane per eigenvector) + rare cluster re-orth --------
// THIS ROUND: ud stores the RECIPROCAL pivot (computed with the one divide the
// factorization already pays) -> back-substitution's 3x575 divides become
// multiplies, cutting its serial chain ~5x. (<=1.5ulp per op difference.)
__global__ void k_eigvecs(const double* __restrict__ dT, const double* __restrict__ eT,
    const double* __restrict__ eval,
    double* __restrict__ Ud, double* __restrict__ U1, double* __restrict__ U2,
    double* __restrict__ Um, int* __restrict__ Ufl, double* __restrict__ Yv,
    double* __restrict__ Z) {
  __shared__ double sd[N_], se[N_];
  __shared__ double red0;
  __shared__ int cstart[G_];
  __shared__ double sh_ev[G_];
  int b = blockIdx.x;
  for (int i = threadIdx.x; i < N_; i += blockDim.x) {
    sd[i] = dT[(size_t)b*N_ + i]; se[i] = eT[(size_t)b*N_ + i];
  }
  if (threadIdx.x < G_) sh_ev[threadIdx.x] = eval[(size_t)b*G_ + threadIdx.x];
  __syncthreads();
  int j = threadIdx.x;
  size_t sbase = (size_t)b * N_ * G_;
  double* ud = Ud + sbase; double* u1 = U1 + sbase; double* u2 = U2 + sbase;
  double* um = Um + sbase; int* ufl = Ufl + sbase; double* yv = Yv + sbase;
  if (j < G_) {
    double lam = sh_ev[j];
    double GU = 1e-30 * (1.0 + fabs(lam));
    double ak = sd[0] - lam;
    double bk = se[0];
    for (int k = 0; k < N_ - 1; k++) {
      double sub = se[k];
      double diag1 = sd[k+1] - lam;
      double sup1 = (k < N_ - 2) ? se[k+1] : 0.0;
      double udv, u1v, u2v, umv; int flv;
      if (fabs(ak) >= fabs(sub)) {
        double piv = ak;
        if (fabs(piv) < GU) piv = (piv >= 0.0) ? GU : -GU;
        double rp = 1.0 / piv;
        double ml = sub * rp;
        udv = rp; u1v = bk; u2v = 0.0; umv = ml; flv = 0;
        ak = diag1 - ml * bk; bk = sup1;
      } else {
        double rs = 1.0 / sub;        // flv=1 => |sub| > |ak| >= 0, sub != 0
        double ml = ak * rs;
        udv = rs; u1v = diag1; u2v = sup1; umv = ml; flv = 1;
        ak = bk - ml * diag1; bk = -ml * sup1;
      }
      ud[(size_t)k*G_+j] = udv; u1[(size_t)k*G_+j] = u1v; u2[(size_t)k*G_+j] = u2v;
      um[(size_t)k*G_+j] = umv; ufl[(size_t)k*G_+j] = flv;
    }
    { double piv = ak; if (fabs(piv) < GU) piv = (piv >= 0.0) ? GU : -GU;
      ud[(size_t)(N_-1)*G_+j] = 1.0 / piv; u1[(size_t)(N_-1)*G_+j] = 0.0; u2[(size_t)(N_-1)*G_+j] = 0.0; }
    for (int i = 0; i < N_; i++) {
      unsigned s = (unsigned)(i * 2654435761u) ^ (unsigned)((j + 1) * 40503u) ^ (unsigned)(b * 2246822519u);
      s = s * 1664525u + 1013904223u;
      s ^= s >> 16; s = s * 2246822519u;
      double rv = ((double)(s >> 8) * (1.0 / 16777216.0)) * 2.0 - 1.0;
      if (fabs(rv) < 1e-3) rv = 0.5;
      yv[(size_t)i*G_+j] = rv;
    }
    for (int it = 0; it < 3; it++) {
      if (it) {
        double mx = 0.0;
        for (int i = 0; i < N_; i++) mx = fmax(mx, fabs(yv[(size_t)i*G_+j]));
        double sc = 1.0 / fmax(mx, 1e-300);
        for (int i = 0; i < N_; i++) yv[(size_t)i*G_+j] *= sc;
      }
      // forward elimination, register-carried
      double ykc = yv[0*G_ + j];
      for (int k = 0; k < N_ - 1; k++) {
        double ynx = yv[(size_t)(k+1)*G_+j];   // original value, not on the chain
        double yk = ykc, yk1 = ynx;
        if (ufl[(size_t)k*G_+j]) { yk = ynx; yk1 = ykc; }
        yk1 -= um[(size_t)k*G_+j] * yk;
        yv[(size_t)k*G_+j] = yk;               // final value for row k
        ykc = yk1;                             // becomes next iteration's yk
      }
      // back substitution: multiply by stored reciprocal (no divides on chain)
      double y1, y2 = 0.0;
      { double tt = ykc * ud[(size_t)(N_-1)*G_+j];
        yv[(size_t)(N_-1)*G_+j] = tt; y1 = tt; }
      for (int k = N_ - 2; k >= 0; k--) {
        double tt = yv[(size_t)k*G_+j] - u1[(size_t)k*G_+j]*y1 - u2[(size_t)k*G_+j]*y2;
        tt *= ud[(size_t)k*G_+j];
        yv[(size_t)k*G_+j] = tt;
        y2 = y1; y1 = tt;
      }
    }
    double s2 = 0.0;
    for (int i = 0; i < N_; i++) { double tt = yv[(size_t)i*G_+j]; s2 += tt * tt; }
    double inv = 1.0 / sqrt(fmax(s2, 1e-300));
    double* Zj = Z + ((size_t)b*G_ + j) * N_;
    for (int i = 0; i < N_; i++) Zj[i] = yv[(size_t)i*G_+j] * inv;
  }
  __syncthreads();
  if (threadIdx.x == 0) {
    double tol = 1e-10 * (fabs(sh_ev[0]) + 1.0);
    cstart[0] = 0;
    for (int q = 1; q < G_; q++)
      cstart[q] = ((sh_ev[q-1] - sh_ev[q]) < tol) ? cstart[q-1] : q;
  }
  __syncthreads();
  for (int q = 1; q < G_; q++) {
    if (cstart[q] == q) continue;
    double* Zq = Z + ((size_t)b*G_ + q) * N_;
    for (int p = cstart[q]; p < q; p++) {
      double* Zp = Z + ((size_t)b*G_ + p) * N_;
      double dp = 0.0;
      for (int i = threadIdx.x; i < N_; i += blockDim.x) dp += Zq[i] * Zp[i];
      for (int o = 32; o > 0; o >>= 1) dp += __shfl_down(dp, o);
      if (threadIdx.x == 0) red0 = dp;
      __syncthreads();
      double dd = red0;
      for (int i = threadIdx.x; i < N_; i += blockDim.x) Zq[i] -= dd * Zp[i];
      __syncthreads();
    }
    double s2 = 0.0;
    for (int i = threadIdx.x; i < N_; i += blockDim.x) { double tt = Zq[i]; s2 += tt * tt; }
    for (int o = 32; o > 0; o >>= 1) s2 += __shfl_down(s2, o);
    if (threadIdx.x == 0) red0 = s2;
    __syncthreads();
    double inv = 1.0 / sqrt(fmax(red0, 1e-300));
    for (int i = threadIdx.x; i < N_; i += blockDim.x) Zq[i] *= inv;
    __syncthreads();
  }
}

// -------- K8: back-transform, one wave per (batch, eigenvector), Z in registers --------
__global__ __launch_bounds__(64) void k_backxf_mb(const double* __restrict__ Aall,
    const double* __restrict__ tauT, double* __restrict__ Z) {
  int blk = blockIdx.x;
  int b = blk / G_, q = blk % G_;
  const double* A = Aall + (size_t)b*N_*N_;
  const double* tau = tauT + (size_t)b*N_;
  double* Zq = Z + ((size_t)b*G_ + q) * N_;
  int lane = threadIdx.x;
  double z[9];
#pragma unroll
  for (int m = 0; m < 9; m++) z[m] = Zq[lane + 64*m];
  for (int k = N_ - 3; k >= 0; k--) {
    double t = tau[k];
    if (t == 0.0) continue;
    const double* vk = A + (size_t)k*N_;
    double vv[9]; double p = 0.0;
#pragma unroll
    for (int m = 0; m < 9; m++) {
      int i = lane + 64*m;
      double vi = (i > k) ? vk[i] : 0.0;
      vv[m] = vi; p += vi * z[m];
    }
    for (int o = 32; o > 0; o >>= 1) p += __shfl_down(p, o);
    p = __shfl(p, 0);
    double s = t * p;
#pragma unroll
    for (int m = 0; m < 9; m++) z[m] -= s * vv[m];
  }
#pragma unroll
  for (int m = 0; m < 9; m++) Zq[lane + 64*m] = z[m];
}

// -------- K9: belong = argmax_q |V[n][q]| (first max) --------
__global__ void k_belong(const double* __restrict__ Z, int* __restrict__ belong) {
  int idx = blockIdx.x * blockDim.x + threadIdx.x;
  if (idx >= B_ * N_) return;
  int b = idx / N_, n = idx % N_;
  const double* Zb = Z + (size_t)b*G_*N_;
  double best = -1.0; int bi = 0;
  for (int q = 0; q < G_; q++) {
    double av = fabs(Zb[(size_t)q*N_ + n]);
    if (av > best) { best = av; bi = q; }
  }
  belong[idx] = bi;
}

// -------- K10: NMS + quota scheduling + index emission (one block per batch) --------
__global__ __launch_bounds__(256) void k_nms(const float* __restrict__ sim,
    const float* __restrict__ cls, const int* __restrict__ belong,
    const float* __restrict__ thrF, float* __restrict__ outF) {
  __shared__ float nsv[N_], rsv[N_];
  __shared__ int bl_s[N_];
  __shared__ int lists[N_];
  __shared__ int off[G_ + 1];
  __shared__ int kc[G_], gc[G_], lowv[G_], upv[G_], tokd[G_], sortg[G_], pre[G_ + 1];
  __shared__ int gathered[L_];
  __shared__ int anyv;
  __shared__ float shthr;
  int b = blockIdx.x, tid = threadIdx.x;
  const float* simb = sim + (size_t)b*N_*N_;
  if (tid == 0) shthr = thrF[b];
  if (tid < G_) gc[tid] = 0;
  __syncthreads();
  for (int i = tid; i < N_; i += 256) {
    int g = belong[b*N_ + i];
    bl_s[i] = g;
    float sc = cls[b*N_ + i];
    nsv[i] = sc; rsv[i] = sc;
    atomicAdd(&gc[g], 1);
  }
  __syncthreads();
  if (tid == 0) {           // deterministic (ascending-n) group list build
    off[0] = 0;
    for (int g = 0; g < G_; g++) off[g+1] = off[g] + gc[g];
    for (int g = 0; g < G_; g++) pre[g] = off[g];
    for (int n = 0; n < N_; n++) lists[pre[bl_s[n]]++] = n;
  }
  __syncthreads();
  float thr = shthr;
  float gs = 1000.0f;
  int myc = 0;
  for (int iter = 0; iter < N_ + 8; iter++) {
    if (tid == 0) anyv = 0;
    __syncthreads();
    int m = -1;
    if (tid < G_) {
      float mx = 0.0f;
      for (int a = off[tid]; a < off[tid+1]; a++) {
        int n2 = lists[a];
        float vv = nsv[n2];
        if (vv > mx) { mx = vv; m = n2; }
      }
      if (m >= 0) anyv = 1;
    }
    __syncthreads();
    if (m >= 0) {
      rsv[m] = gs;
      nsv[m] = 0.0f;
      const float* srow = simb + (size_t)m*N_;
      for (int a = off[tid]; a < off[tid+1]; a++) {
        int n2 = lists[a];
        if (nsv[n2] > 0.0f && srow[n2] > thr) nsv[n2] = 0.0f;
      }
      myc++;
    }
    gs -= 1.0f;
    __syncthreads();
    if (!anyv) break;
  }
  if (tid < G_) kc[tid] = myc;
  __syncthreads();
  if (tid == 0) {
    int sumkc = 0; for (int g = 0; g < G_; g++) sumkc += kc[g];
    int sumlow = 0;
    for (int g = 0; g < G_; g++) {
      lowv[g] = (gc[g] < 1) ? gc[g] : 1;
      int u = 15; if (gc[g] < u) u = gc[g]; if (kc[g] < u) u = kc[g];
      upv[g] = u; sumlow += lowv[g];
    }
    int su = 0; for (int g = 0; g < G_; g++) su += upv[g];
    while (su < NEED_) {
      su = 0;
      for (int g = 0; g < G_; g++) { int u = upv[g] + 1; if (u > gc[g]) u = gc[g]; upv[g] = u; su += u; }
    }
    int other = NEED_ - sumlow - 1; if (other < 0) other = 0;
    float s = (float)sumkc;
    float c = 0.0f; int prevR = 0;
    float otherf = (float)other;
    for (int g = 0; g < G_; g++) {
      float nc = (float)kc[g] / s;
      c += nc;
      int R = (int)rintf(c * otherf);          // round half-to-even like jnp.round
      int od = R - prevR; prevR = R;
      int t0 = od + lowv[g]; if (t0 > upv[g]) t0 = upv[g];
      tokd[g] = t0;
    }
    for (int g = 0; g < G_; g++) sortg[g] = g;
    for (int a = 1; a < G_; a++) {            // stable insertion sort, kc descending
      int vIdx = sortg[a]; int key = kc[vIdx]; int p2 = a - 1;
      while (p2 >= 0 && kc[sortg[p2]] < key) { sortg[p2+1] = sortg[p2]; p2--; }
      sortg[p2+1] = vIdx;
    }
    int target = other + sumlow;
    int sumd = 0; for (int g = 0; g < G_; g++) sumd += tokd[g];
    int fg = 0;
    while (sumd < target) {
      int gi = sortg[(fg < G_-1) ? fg : (G_-1)];
      int fill = upv[gi] - tokd[gi];
      int rem = target - sumd;
      if (rem < fill) fill = rem;
      tokd[gi] += fill; sumd += fill;
      fg++;
      if (fg > 100000) break;
    }
    pre[0] = 0; for (int g = 0; g < G_; g++) pre[g+1] = pre[g] + tokd[g];
  }
  __syncthreads();
  for (int i = tid; i < L_; i += 256) gathered[i] = 0;
  __syncthreads();
  if (tid < G_) {
    int g = tid;
    int td = tokd[g], base = pre[g];
    for (int t = 0; t < td; t++) {
      float bv = -3e38f; int bn2 = 0;
      for (int a = off[g]; a < off[g+1]; a++) {
        int n2 = lists[a];
        float vv = rsv[n2];
        if (vv > bv) { bv = vv; bn2 = n2; }
      }
      rsv[bn2] = -3e38f;
      int pos = base + t;
      if (pos < L_) gathered[pos] = bn2;
    }
  }
  __syncthreads();
  if (tid < NEED_) {
    float val = (tid == 0) ? 0.0f : (float)(gathered[tid - 1] + 1);
    outF[(size_t)B_*NEED_*D_ + (size_t)b*NEED_ + tid] = val;
  }
}

// -------- K11: gather selected hidden rows --------
__global__ void k_gather(const float* __restrict__ hs, float* __restrict__ outF) {
  int blk = blockIdx.x;
  int b = blk / NEED_, i = blk % NEED_;
  int idx = (int)outF[(size_t)B_*NEED_*D_ + (size_t)b*NEED_ + i];
  const float4* src = (const float4*)(hs + ((size_t)b*T_ + idx) * (size_t)D_);
  float4* dst = (float4*)(outF + ((size_t)b*NEED_ + i) * (size_t)D_);
  dst[threadIdx.x] = src[threadIdx.x];
}

extern "C" void kernel_launch(void* const* d_in, const int* in_sizes, int n_in,
                              void* d_out, int out_size, void* d_ws, size_t ws_size,
                              hipStream_t stream) {
  if (ws_size < WS_NEEDED) return;
  const float* hs   = (const float*)d_in[0];
  const float* attn = (const float*)d_in[1];
  float* outF = (float*)d_out;
  char* w = (char*)d_ws;
  float*  msig = (float*)(w + OF_MSIG);
  float*  sim  = (float*)(w + OF_SIM);
  double* A    = (double*)(w + OF_A);
  double* ms   = (double*)(w + OF_MS);
  double* invn = (double*)(w + OF_INVN);
  float*  cls  = (float*)(w + OF_CLS);
  double* dT   = (double*)(w + OF_DT);
  double* eT   = (double*)(w + OF_ET);
  double* tauT = (double*)(w + OF_TAU);
  double* eval = (double*)(w + OF_EVAL);
  double* Z    = (double*)(w + OF_Z);
  double* part = (double*)(w + OF_PART);
  float*  thrF = (float*)(w + OF_THR);
  int*    belong = (int*)(w + OF_BEL);
  int*    bars = (int*)(w + OF_BAR);
  double* wb   = (double*)(w + OF_WB);
  double* pv   = (double*)(w + OF_PV_ALIAS);   // dead msig region during tridiag
  // inverse-iteration scratch aliases msig region (msig dead after the Gram GEMM)
  double* Ud = (double*)(w + OF_MSIG);
  double* U1 = Ud + (size_t)B_*N_*G_;
  double* U2 = U1 + (size_t)B_*N_*G_;
  double* Um = U2 + (size_t)B_*N_*G_;
  double* Yv = Um + (size_t)B_*N_*G_;
  int*    Ufl = (int*)(Yv + (size_t)B_*N_*G_);

  k_prep<<<B_*N_, 256, 0, stream>>>(hs, msig, ms, invn, bars);
  k_cls<<<(B_*N_ + 255)/256, 256, 0, stream>>>(attn, cls);
  k_gemm<<<dim3(N_/32, N_/32, B_), 256, 0, stream>>>(hs, msig, ms, invn, A, sim, 0);
  k_gemm<<<dim3(N_/32, N_/32, B_), 256, 0, stream>>>(hs, msig, ms, invn, A, sim, 1);
  k_simsum<<<B_*36, 256, 0, stream>>>(sim, part);
  k_thr<<<1, 64, 0, stream>>>(part, thrF);
  k_tridiag_mb<<<B_*NB_, 512, 0, stream>>>(A, dT, eT, tauT, pv, wb, bars);
  k_eigvals_ms<<<B_*G_, 64, 0, stream>>>(dT, eT, eval);
  k_eigvecs<<<B_, 64, 0, stream>>>(dT, eT, eval, Ud, U1, U2, Um, Ufl, Yv, Z);
  k_backxf_mb<<<B_*G_, 64, 0, stream>>>(A, tauT, Z);
  k_belong<<<(B_*N_ + 255)/256, 256, 0, stream>>>(Z, belong);
  k_nms<<<B_, 256, 0, stream>>>(sim, cls, belong, thrF, outF);
  k_gather<<<B_*NEED_, 256, 0, stream>>>(hs, outF);
}

// Round 8
// 7225.369 us; speedup vs baseline: 1.0561x; 1.0176x over previous
//
#include <hip/hip_runtime.h>
#include <math.h>

// Problem constants
constexpr int B_ = 4, T_ = 577, N_ = 576, D_ = 1024, G_ = 48, H_ = 16;
constexpr int NEED_ = 192, L_ = 191;
constexpr int TRIU_CNT = N_ * (N_ - 1) / 2; // 165600
constexpr int NB_ = 8;                      // blocks per batch in tridiag (512 thr each)
constexpr int NBAR_ = 640;                  // barrier slots per batch (1 per step)

// Fused-dispatch block ranges: [0,32) tridiag | [32, 32+1296) sim-GEMM | cls
constexpr int TRI_BLKS = B_ * NB_;                  // 32
constexpr int GM_BX = N_ / 32;                      // 18
constexpr int GM_BLKS = GM_BX * GM_BX * B_;         // 1296
constexpr int CLS_BLKS = (B_ * N_ + 511) / 512;     // 5
constexpr int FUSED_BLKS = TRI_BLKS + GM_BLKS + CLS_BLKS;

// ---------------- workspace layout (bytes) ----------------
constexpr size_t OF_MSIG = 0;                                    // f32 B*N*D (dead after GEMM; aliased: invit scratch @0, pv @8MB)
constexpr size_t OF_SIM  = OF_MSIG + (size_t)B_*N_*D_*4;
constexpr size_t OF_A    = OF_SIM  + (size_t)B_*N_*N_*4;         // f64 Gram (rows also hold archived reflectors)
constexpr size_t OF_MS   = OF_A    + (size_t)B_*N_*N_*8;         // f64 sigmoid row sums
constexpr size_t OF_INVN = OF_MS   + (size_t)B_*N_*8;            // f64 1/norm of raw hs rows
constexpr size_t OF_CLS  = OF_INVN + (size_t)B_*N_*8;            // f32 cls attention sums
constexpr size_t OF_DT   = OF_CLS  + (size_t)B_*N_*4;            // f64 tridiag diagonal
constexpr size_t OF_ET   = OF_DT   + (size_t)B_*N_*8;            // f64 tridiag off-diagonal
constexpr size_t OF_TAU  = OF_ET   + (size_t)B_*N_*8;            // f64 Householder taus
constexpr size_t OF_EVAL = OF_TAU  + (size_t)B_*N_*8;            // f64 top-48 eigenvalues (descending)
constexpr size_t OF_Z    = OF_EVAL + (size_t)B_*G_*8;            // f64 eigenvectors [b][q][i]
constexpr size_t OF_PART = OF_Z    + (size_t)B_*G_*N_*8;         // f64 simmean partials B*36
constexpr size_t OF_THR  = OF_PART + (size_t)B_*36*8;            // f32 thresholds (padded)
constexpr size_t OF_BEL  = OF_THR  + 64;                         // int belong
constexpr size_t OF_BAR  = OF_BEL  + (size_t)B_*N_*4;            // int barrier counters
constexpr size_t OF_FLG  = OF_BAR  + (size_t)B_*NBAR_*4;         // int (legacy, unused)
constexpr size_t OF_VB   = OF_FLG  + (size_t)B_*16*4;            // f64 (legacy, unused)
constexpr size_t OF_WB   = OF_VB   + (size_t)B_*N_*8;            // f64 wbuf ×2 (parity double-buffer)
constexpr size_t OF_SG   = OF_WB   + (size_t)B_*2*N_*8;          // f64 (legacy, unused)
constexpr size_t OF_KP   = OF_SG   + (size_t)B_*8*8;             // f64 (legacy, unused)
constexpr size_t WS_NEEDED = OF_KP + (size_t)B_*2*16*8;

// pv: pivot-row publish buffer, ×2 parity, per batch, in the dead msig region
constexpr size_t OF_PV_ALIAS = OF_MSIG + ((size_t)8 << 20);      // f64 B*2*N

__device__ __forceinline__ double blockReduceD(double x, double* red) {
  int lane = threadIdx.x & 63, wv = threadIdx.x >> 6;
  int nw = (blockDim.x + 63) >> 6;
  for (int o = 32; o > 0; o >>= 1) x += __shfl_down(x, o);
  __syncthreads();                // protect red from previous use
  if (lane == 0) red[wv] = x;
  __syncthreads();
  double t = red[0];
  for (int i = 1; i < nw; i++) t += red[i];
  return t;                       // same deterministic value on all threads/blocks
}

// 4-value block reduction in one LDS round (deterministic, identical per block)
__device__ __forceinline__ void blockReduce4(double& x0, double& x1, double& x2,
                                             double& x3, double* red) {
  int lane = threadIdx.x & 63, wv = threadIdx.x >> 6;
  int nw = (blockDim.x + 63) >> 6;
  for (int o = 32; o > 0; o >>= 1) {
    x0 += __shfl_down(x0, o); x1 += __shfl_down(x1, o);
    x2 += __shfl_down(x2, o); x3 += __shfl_down(x3, o);
  }
  __syncthreads();
  if (lane == 0) { red[wv*4+0]=x0; red[wv*4+1]=x1; red[wv*4+2]=x2; red[wv*4+3]=x3; }
  __syncthreads();
  double t0 = red[0], t1 = red[1], t2 = red[2], t3 = red[3];
  for (int i = 1; i < nw; i++) {
    t0 += red[i*4+0]; t1 += red[i*4+1]; t2 += red[i*4+2]; t3 += red[i*4+3];
  }
  x0 = t0; x1 = t1; x2 = t2; x3 = t3;
}

// coherent (agent-scope, cache-bypassing) load/store for cross-block data
__device__ __forceinline__ double cload(const double* p) {
  return __hip_atomic_load(p, __ATOMIC_RELAXED, __HIP_MEMORY_SCOPE_AGENT);
}
__device__ __forceinline__ void cstore(double* p, double x) {
  __hip_atomic_store(p, x, __ATOMIC_RELAXED, __HIP_MEMORY_SCOPE_AGENT);
}

// device barrier among the NB_ blocks of one batch (R1/R3-measured design).
__device__ __forceinline__ void gbar(int* bar, int slot, int tid) {
  __syncthreads();
  if (tid == 0) {
    __hip_atomic_fetch_add(&bar[slot], 1, __ATOMIC_RELAXED, __HIP_MEMORY_SCOPE_AGENT);
    while (__hip_atomic_load(&bar[slot], __ATOMIC_ACQUIRE, __HIP_MEMORY_SCOPE_AGENT) < NB_)
      __builtin_amdgcn_s_sleep(2);
  }
  __syncthreads();
  __asm__ volatile("" ::: "memory");
}

// -------- K1: sigmoid features, row sums, inverse norms (+ zero barrier slots) --------
__global__ void k_prep(const float* __restrict__ hs, float* __restrict__ msig,
                       double* __restrict__ ms, double* __restrict__ invn,
                       int* __restrict__ bars) {
  __shared__ double red[16];
  if (blockIdx.x == 0) {
    for (int i = threadIdx.x; i < B_ * NBAR_; i += blockDim.x) bars[i] = 0;
  }
  int bn = blockIdx.x; int b = bn / N_, n = bn % N_;
  const float* row = hs + ((size_t)b*T_ + (n+1)) * (size_t)D_;
  float* mrow = msig + (size_t)bn * D_;
  double ssig = 0.0, ssq = 0.0;
  for (int d = threadIdx.x; d < D_; d += blockDim.x) {
    float x = row[d];
    float sg = 1.0f / (1.0f + expf(-x));
    mrow[d] = sg;
    ssig += (double)sg;
    ssq  += (double)x * (double)x;
  }
  double tot_sig = blockReduceD(ssig, red);
  double tot_sq  = blockReduceD(ssq, red);
  if (threadIdx.x == 0) {
    ms[bn] = tot_sig;
    invn[bn] = 1.0 / fmax(sqrt(tot_sq), 1e-12);
  }
}

// -------- K3: tiled X*X^T GEMM, mode0 only (f64 Gram; runs before tridiag) --------
__global__ void k_gemm(const float* __restrict__ hs, const float* __restrict__ msig,
                       const double* __restrict__ ms, const double* __restrict__ invn,
                       double* __restrict__ Aout, float* __restrict__ sim, int mode) {
  __shared__ float As[32][17], Bs[32][17];
  int b = blockIdx.z;
  int bi0 = blockIdx.y * 32, bj0 = blockIdx.x * 32;
  const float* base = (mode == 0) ? (msig + (size_t)b*N_*D_)
                                  : (hs + ((size_t)b*T_ + 1) * (size_t)D_);
  int tid = threadIdx.x;
  int tx = tid & 15, ty = tid >> 4;
  double a00 = 0, a01 = 0, a10 = 0, a11 = 0;
  for (int k0 = 0; k0 < D_; k0 += 16) {
    int r = tid >> 4, c = tid & 15;
    As[r][c] = base[(size_t)(bi0 + r) * D_ + k0 + c];
    Bs[r][c] = base[(size_t)(bj0 + r) * D_ + k0 + c];
    int e = tid + 256; r = e >> 4; c = e & 15;
    As[r][c] = base[(size_t)(bi0 + r) * D_ + k0 + c];
    Bs[r][c] = base[(size_t)(bj0 + r) * D_ + k0 + c];
    __syncthreads();
#pragma unroll
    for (int kk = 0; kk < 16; kk++) {
      double x0 = As[2*ty][kk],   x1 = As[2*ty+1][kk];
      double y0 = Bs[2*tx][kk],   y1 = Bs[2*tx+1][kk];
      a00 += x0*y0; a01 += x0*y1; a10 += x1*y0; a11 += x1*y1;
    }
    __syncthreads();
  }
  int i0 = bi0 + 2*ty, j0 = bj0 + 2*tx;
  if (mode == 0) {
    const double* msb = ms + (size_t)b*N_;
    double* Ab = Aout + (size_t)b*N_*N_;
    const double inv1024 = 1.0 / 1024.0;
    Ab[(size_t)i0*N_ + j0]         = a00 - msb[i0]*msb[j0]*inv1024;
    Ab[(size_t)i0*N_ + j0+1]       = a01 - msb[i0]*msb[j0+1]*inv1024;
    Ab[(size_t)(i0+1)*N_ + j0]     = a10 - msb[i0+1]*msb[j0]*inv1024;
    Ab[(size_t)(i0+1)*N_ + j0+1]   = a11 - msb[i0+1]*msb[j0+1]*inv1024;
  } else {
    const double* iv = invn + (size_t)b*N_;
    float* sb = sim + (size_t)b*N_*N_;
    sb[(size_t)i0*N_ + j0]       = (float)(a00 * iv[i0]*iv[j0]);
    sb[(size_t)i0*N_ + j0+1]     = (float)(a01 * iv[i0]*iv[j0+1]);
    sb[(size_t)(i0+1)*N_ + j0]   = (float)(a10 * iv[i0+1]*iv[j0]);
    sb[(size_t)(i0+1)*N_ + j0+1] = (float)(a11 * iv[i0+1]*iv[j0+1]);
  }
}

// -------- K4: upper-triangle sum partials --------
__global__ void k_simsum(const float* __restrict__ sim, double* __restrict__ part) {
  __shared__ double red[4];
  int blk = blockIdx.x; int b = blk / 36, s = blk % 36;
  const float* sb = sim + (size_t)b*N_*N_;
  double p = 0.0;
  for (int i = s*16; i < s*16 + 16; i++) {
    const float* row = sb + (size_t)i*N_;
    for (int j = i + 1 + threadIdx.x; j < N_; j += blockDim.x) p += (double)row[j];
  }
  double t = blockReduceD(p, red);
  if (threadIdx.x == 0) part[blk] = t;
}

__global__ void k_thr(const double* __restrict__ part, float* __restrict__ thrF) {
  int b = threadIdx.x;
  if (b < B_) {
    double s = 0.0;
    for (int i = 0; i < 36; i++) s += part[b*36 + i];
    thrF[b] = 6.0f * (float)(s / (double)TRIU_CNT);
  }
}

// -------- K5 (FUSED): tridiag (blocks 0..31) ∥ sim-GEMM (next 1296) ∥ cls (last 5) --------
// Tridiag path is the R5-verified structure, byte-identical logic. The sim-GEMM
// and cls blocks run on the ~224 CUs that tridiag leaves idle; they touch only
// hs/invn/sim and attn/cls — fully disjoint from tridiag's A/wb/pv/bars, no
// cross-role sync. LDS overlaid via union (tridiag footprint, ~23.8KB).
union __align__(16) SharedU {
  struct {
    double rb[3][N_];      // v_prev / v_cur(=r1) / r2  (offset 0, 16B-aligned)
    double wwb[2][N_];     // w parity: prev / cur      (offset 13824, 16B-aligned)
    double red[32];
    double nx0s;
  } tri;
  struct {
    float As[32][17];
    float Bs[32][17];
  } gm;
};

__global__ __launch_bounds__(512) void k_tridiag_mb(double* __restrict__ Aall,
    double* __restrict__ dT, double* __restrict__ eT, double* __restrict__ tauT,
    double* __restrict__ pv_all, double* __restrict__ wb_all,
    int* __restrict__ bars,
    const float* __restrict__ hs, const double* __restrict__ invn,
    float* __restrict__ sim, const float* __restrict__ attn,
    float* __restrict__ cls) {
  __shared__ SharedU sh;
  int tid = threadIdx.x;

  // ================= role: sim-GEMM (mode 1) =================
  if (blockIdx.x >= TRI_BLKS && blockIdx.x < TRI_BLKS + GM_BLKS) {
    int gblk = blockIdx.x - TRI_BLKS;
    int bx = gblk % GM_BX, by = (gblk / GM_BX) % GM_BX, b = gblk / (GM_BX * GM_BX);
    int bi0 = by * 32, bj0 = bx * 32;
    const float* base = hs + ((size_t)b*T_ + 1) * (size_t)D_;
    float (&As)[32][17] = sh.gm.As;
    float (&Bs)[32][17] = sh.gm.Bs;
    int tx = tid & 15, ty = (tid < 256) ? (tid >> 4) : 0;
    double a00 = 0, a01 = 0, a10 = 0, a11 = 0;
    int r = tid >> 5;            // 512 threads: r = tid>>5? no — keep original mapping
    // load mapping: 512 threads cover the 32x16 tile once (r=tid>>4 in 0..31)
    for (int k0 = 0; k0 < D_; k0 += 16) {
      int lr = tid >> 4, lc = tid & 15;   // 0..31, 0..15
      As[lr][lc] = base[(size_t)(bi0 + lr) * D_ + k0 + lc];
      Bs[lr][lc] = base[(size_t)(bj0 + lr) * D_ + k0 + lc];
      __syncthreads();
      if (tid < 256) {
#pragma unroll
        for (int kk = 0; kk < 16; kk++) {
          double x0 = As[2*ty][kk],   x1 = As[2*ty+1][kk];
          double y0 = Bs[2*tx][kk],   y1 = Bs[2*tx+1][kk];
          a00 += x0*y0; a01 += x0*y1; a10 += x1*y0; a11 += x1*y1;
        }
      }
      __syncthreads();
    }
    if (tid < 256) {
      int i0 = bi0 + 2*ty, j0 = bj0 + 2*tx;
      const double* iv = invn + (size_t)b*N_;
      float* sb = sim + (size_t)b*N_*N_;
      sb[(size_t)i0*N_ + j0]       = (float)(a00 * iv[i0]*iv[j0]);
      sb[(size_t)i0*N_ + j0+1]     = (float)(a01 * iv[i0]*iv[j0+1]);
      sb[(size_t)(i0+1)*N_ + j0]   = (float)(a10 * iv[i0+1]*iv[j0]);
      sb[(size_t)(i0+1)*N_ + j0+1] = (float)(a11 * iv[i0+1]*iv[j0+1]);
    }
    return;
  }

  // ================= role: cls attention sums =================
  if (blockIdx.x >= TRI_BLKS + GM_BLKS) {
    int idx = (blockIdx.x - (TRI_BLKS + GM_BLKS)) * 512 + tid;
    if (idx < B_ * N_) {
      int b = idx / N_, n = idx % N_;
      float s = 0.0f;
      for (int h = 0; h < H_; h++)
        s += attn[(((size_t)b*H_ + h) * T_ + 0) * T_ + (1 + n)];
      cls[idx] = s;
    }
    return;
  }

  // ================= role: tridiag (R5-verified, logic unchanged) =================
  double (&rb)[3][N_] = sh.tri.rb;
  double (&wwb)[2][N_] = sh.tri.wwb;
  double* red = sh.tri.red;
  int blk = blockIdx.x;
  int b = blk % B_;          // batch: clusters each batch's blocks on 2 XCDs
  int t = blk / B_;          // 0..NB_-1
  double* A  = Aall + (size_t)b*N_*N_;
  double* dv = dT   + (size_t)b*N_;
  double* ev = eT   + (size_t)b*N_;
  double* tv = tauT + (size_t)b*N_;
  double* pvB = pv_all + (size_t)b*2*N_;
  double* wbB = wb_all + (size_t)b*2*N_;
  int* bar = bars + b*NBAR_;
  int lane = tid & 63, wv = tid >> 6;

  // ---- prologue: r1 <- row 0, r2 <- row 1, zero prev-v/prev-w, sigma_0 ----
  double sig;
  {
    double ps = 0.0;
    if (tid == 0) sh.tri.nx0s = A[1];   // x0 for step 0 (ordered by reduce's barrier)
    for (int j = tid; j < N_; j += 512) {
      rb[0][j] = 0.0;             // v_prev for step 0
      wwb[1][j] = 0.0;            // w_prev for step 0
      double a0 = A[j];
      rb[1][j] = a0;
      rb[2][j] = A[(size_t)N_ + j];
      if (j >= 1) ps += a0 * a0;
    }
    sig = blockReduceD(ps, red);
  }

  for (int k = 0; k < N_ - 2; k++) {
    int rot = k % 3;
    double* vp = rb[rot];             // v_{k-1}
    double* vc = rb[(rot + 1) % 3];   // r1 = row k (state k-1); becomes v_k
    double* r2 = rb[(rot + 2) % 3];   // row k+1 (state k-1)
    double* wp = wwb[(k & 1) ^ 1];    // w_{k-1}
    double* wc = wwb[k & 1];          // w_k
    double* wbk = wbB + (size_t)(k & 1) * N_;
    double* pvk = pvB + (size_t)(k & 1) * N_;

    // ---- phase A: Householder scalars, local & identical per block ----
    double sigma = sig;
    double x0 = sh.tri.nx0s;          // no thread reads vc[k+1] -> no pre-write barrier
    double alpha, tauk;
    if (sigma == 0.0) { alpha = 0.0; tauk = 0.0; }
    else {
      alpha = (x0 >= 0.0) ? -sqrt(sigma) : sqrt(sigma);
      tauk = 1.0 / (sigma - alpha * x0);
    }
    if (tid == 0) {
      vc[k + 1] = x0 - alpha;
      if (t == 0) { dv[k] = vc[k]; ev[k] = alpha; tv[k] = tauk; }
    }
    __syncthreads();

    // ---- phase B: fused (prev rank-2) + (matvec with v_k), double2; pv publish ----
    int rr = (k + 1) % NB_;
    int rofs = t - rr; if (rofs < 0) rofs += NB_;
    for (int r = (k + 1) + rofs + wv * NB_; r < N_; r += 8 * NB_) {
      double* Ar = A + (size_t)r * N_;
      double vrp = vp[r], wrp = wp[r];
      double pd = 0.0;
      int jbeg = k + 1;
      if (jbeg & 1) {                 // scalar peel to 16B-align the vector loop
        if (lane == 0) {
          double nv = Ar[jbeg] - vrp * wp[jbeg] - wrp * vp[jbeg];
          Ar[jbeg] = nv;
          pd += nv * vc[jbeg];        // j = k+1: never published to pv
        }
        jbeg++;
      }
      if (r == k + 2) {
        for (int j = jbeg + 2 * lane; j < N_; j += 128) {
          double2 av  = *(const double2*)(Ar + j);
          double2 wpv = *(const double2*)(wp + j);
          double2 vpv = *(const double2*)(vp + j);
          double2 vcv = *(const double2*)(vc + j);
          double nv0 = av.x - vrp * wpv.x - wrp * vpv.x;
          double nv1 = av.y - vrp * wpv.y - wrp * vpv.y;
          double2 st; st.x = nv0; st.y = nv1;
          *(double2*)(Ar + j) = st;
          pd += nv0 * vcv.x + nv1 * vcv.y;
          if (j > k + 1) cstore(&pvk[j], nv0);
          cstore(&pvk[j + 1], nv1);   // j+1 >= k+2 always
        }
      } else {
        for (int j = jbeg + 2 * lane; j < N_; j += 128) {
          double2 av  = *(const double2*)(Ar + j);
          double2 wpv = *(const double2*)(wp + j);
          double2 vpv = *(const double2*)(vp + j);
          double2 vcv = *(const double2*)(vc + j);
          double nv0 = av.x - vrp * wpv.x - wrp * vpv.x;
          double nv1 = av.y - vrp * wpv.y - wrp * vpv.y;
          double2 st; st.x = nv0; st.y = nv1;
          *(double2*)(Ar + j) = st;
          pd += nv0 * vcv.x + nv1 * vcv.y;
        }
      }
      for (int o = 32; o > 0; o >>= 1) pd += __shfl_down(pd, o);
      if (lane == 0) cstore(&wbk[r], tauk * pd);
    }
    gbar(bar, k, tid);                // the ONE global sync of the step

    // ---- phase D: issue cloads, archive reflector under their latency, ----
    // ---- ONE reduce, local K/sigma, update replicas ----
    int i0 = k + 1 + tid;
    bool s0 = (i0 < N_), s1 = (i0 + 512 < N_);
    double w0 = s0 ? cload(&wbk[i0]) : 0.0;
    double w1 = s1 ? cload(&wbk[i0 + 512]) : 0.0;
    double p0 = (s0 && tid > 0) ? cload(&pvk[i0]) : 0.0;
    double p1 = s1 ? cload(&pvk[i0 + 512]) : 0.0;
    double wr1 = cload(&wbk[k + 1]);        // broadcast scalars (parallel RTT)
    double wr2 = cload(&wbk[k + 2]);
    // archive reflector over A row k (row k never read again in this kernel;
    // vc array stays intact until next step's phase D, which is past a gbar)
    if ((k % NB_) == t)
      for (int j = k + 1 + tid; j < N_; j += 512) A[(size_t)k * N_ + j] = vc[j];
    double vc0 = s0 ? vc[i0] : 0.0;
    double vc1 = s1 ? vc[i0 + 512] : 0.0;
    double vk1 = vc[k + 1], vk2 = vc[k + 2];
    double r20 = s0 ? r2[i0] : 0.0;
    double r21 = s1 ? r2[i0 + 512] : 0.0;
    double a0v = r20 - vk1 * w0 - wr1 * vc0;
    double a1v = r21 - vk1 * w1 - wr1 * vc1;
    double kd = w0 * vc0 + w1 * vc1;        // j >= k+1
    double sa2 = 0.0, sav = 0.0, sv2 = 0.0; // j >= k+2
    if (s0 && tid > 0) { sa2 += a0v*a0v; sav += a0v*vc0; sv2 += vc0*vc0; }
    if (s1)            { sa2 += a1v*a1v; sav += a1v*vc1; sv2 += vc1*vc1; }
    blockReduce4(kd, sa2, sav, sv2, red);
    double K = 0.5 * tauk * kd;
    double c = 2.0 * K * vk1;
    sig = sa2 + 2.0 * c * sav + c * c * sv2;   // sigma_{k+1}, local scalar
    double wk2 = wr2 - K * vk2;
    if (s0) {
      double wcj = w0 - K * vc0;
      wc[i0] = wcj;
      double nr1v = a0v + c * vc0;             // nr1
      r2[i0] = nr1v;
      if (tid == 1) sh.tri.nx0s = nr1v;        // next step's x0 = r2'[k+2]
      if (tid > 0) vp[i0] = p0 - vk2 * wcj - wk2 * vc0;   // next r2 (row k+2)
    }
    if (s1) {
      double wcj = w1 - K * vc1;
      wc[i0 + 512] = wcj;
      r2[i0 + 512] = a1v + c * vc1;
      vp[i0 + 512] = p1 - vk2 * wcj - wk2 * vc1;
    }
    __syncthreads();
  }

  // ---- epilogue: final d/e from the local replicas (globals are stale) ----
  if (t == 0 && tid == 0) {
    double* r1f = rb[((N_ - 3) + 2) % 3];  // row N-2, final state
    double* r2f = rb[(N_ - 3) % 3];        // row N-1, final state
    dv[N_-2] = r1f[N_-2];
    ev[N_-2] = r1f[N_-1];
    dv[N_-1] = r2f[N_-1];
    ev[N_-1] = 0.0; tv[N_-2] = 0.0; tv[N_-1] = 0.0;
  }
}

// -------- K6: top-48 eigenvalues, 64-point multisection, division-free Sturm --------
__global__ __launch_bounds__(64) void k_eigvals_ms(const double* __restrict__ dT,
    const double* __restrict__ eT, double* __restrict__ eval) {
  __shared__ double sd[N_], se2[N_];
  int blk = blockIdx.x; int b = blk / G_, j = blk % G_;
  int lane = threadIdx.x;
  for (int i = lane; i < N_; i += 64) {
    sd[i] = dT[(size_t)b*N_ + i];
    se2[i] = eT[(size_t)b*N_ + i];          // raw e for bounds; squared below
  }
  __syncthreads();
  double lo = 1e300, hi = -1e300;
  for (int i = lane; i < N_; i += 64) {
    double r = ((i > 0) ? fabs(se2[i-1]) : 0.0) + ((i < N_-1) ? fabs(se2[i]) : 0.0);
    lo = fmin(lo, sd[i] - r); hi = fmax(hi, sd[i] + r);
  }
  for (int o = 32; o > 0; o >>= 1) {
    lo = fmin(lo, __shfl_xor(lo, o));
    hi = fmax(hi, __shfl_xor(hi, o));
  }
  double span = hi - lo + 1e-30;
  lo -= span * 1e-6; hi += span * 1e-6;
  __syncthreads();
  for (int i = lane; i < N_; i += 64) { double e = se2[i]; se2[i] = e * e; }
  __syncthreads();
  int target = N_ - 1 - j;  // ascending index of j-th largest
  for (int round = 0; round < 9; round++) {
    double width = hi - lo;
    double mid = lo + width * ((double)(lane + 1) / 65.0);
    double pm1 = 1.0;
    double pcur = sd[0] - mid;
    int cnt = (pcur <= 0.0) ? 1 : 0;
    if (pcur == 0.0) pcur = -1e-300;
    for (int i = 1; i < N_; i++) {
      double pnew = (sd[i] - mid) * pcur - se2[i-1] * pm1;
      bool chg = ((pnew < 0.0) != (pcur < 0.0)) || (pnew == 0.0);
      cnt += chg ? 1 : 0;
      if (pnew == 0.0) pnew = (pcur < 0.0) ? 1e-300 : -1e-300; // sign after change
      pm1 = pcur; pcur = pnew;
      if ((i & 3) == 3) {
        double ap = fmax(fabs(pcur), fabs(pm1));
        double s = (ap > 1e160) ? 1e-160 : ((ap < 1e-160) ? 1e160 : 1.0);
        if (s != 1.0) {
          pcur *= s; pm1 *= s;
          if (pcur == 0.0) pcur = (pm1 < 0.0) ? 1e-300 : -1e-300;
          if (pm1 == 0.0)  pm1  = (pcur < 0.0) ? 1e-300 : -1e-300;
        }
      }
    }
    unsigned long long mask = __ballot(cnt > target);
    double nlo, nhi;
    if (mask == 0ULL) { nlo = lo + width * (64.0 / 65.0); nhi = hi; }
    else {
      int m = __ffsll(mask) - 1;
      nhi = lo + width * ((double)(m + 1) / 65.0);
      nlo = (m == 0) ? lo : lo + width * ((double)m / 65.0);
    }
    lo = nlo; hi = nhi;
  }
  if (lane == 0) eval[(size_t)b*G_ + j] = 0.5 * (lo + hi);
}

// -------- K7: inverse iteration (lane per eigenvector) + rare cluster re-orth --------
__global__ void k_eigvecs(const double* __restrict__ dT, const double* __restrict__ eT,
    const double* __restrict__ eval,
    double* __restrict__ Ud, double* __restrict__ U1, double* __restrict__ U2,
    double* __restrict__ Um, int* __restrict__ Ufl, double* __restrict__ Yv,
    double* __restrict__ Z) {
  __shared__ double sd[N_], se[N_];
  __shared__ double red0;
  __shared__ int cstart[G_];
  __shared__ double sh_ev[G_];
  int b = blockIdx.x;
  for (int i = threadIdx.x; i < N_; i += blockDim.x) {
    sd[i] = dT[(size_t)b*N_ + i]; se[i] = eT[(size_t)b*N_ + i];
  }
  if (threadIdx.x < G_) sh_ev[threadIdx.x] = eval[(size_t)b*G_ + threadIdx.x];
  __syncthreads();
  int j = threadIdx.x;
  size_t sbase = (size_t)b * N_ * G_;
  double* ud = Ud + sbase; double* u1 = U1 + sbase; double* u2 = U2 + sbase;
  double* um = Um + sbase; int* ufl = Ufl + sbase; double* yv = Yv + sbase;
  if (j < G_) {
    double lam = sh_ev[j];
    double GU = 1e-30 * (1.0 + fabs(lam));
    double ak = sd[0] - lam;
    double bk = se[0];
    for (int k = 0; k < N_ - 1; k++) {
      double sub = se[k];
      double diag1 = sd[k+1] - lam;
      double sup1 = (k < N_ - 2) ? se[k+1] : 0.0;
      double udv, u1v, u2v, umv; int flv;
      if (fabs(ak) >= fabs(sub)) {
        double piv = ak;
        if (fabs(piv) < GU) piv = (piv >= 0.0) ? GU : -GU;
        double rp = 1.0 / piv;
        double ml = sub * rp;
        udv = rp; u1v = bk; u2v = 0.0; umv = ml; flv = 0;
        ak = diag1 - ml * bk; bk = sup1;
      } else {
        double rs = 1.0 / sub;        // flv=1 => |sub| > |ak| >= 0, sub != 0
        double ml = ak * rs;
        udv = rs; u1v = diag1; u2v = sup1; umv = ml; flv = 1;
        ak = bk - ml * diag1; bk = -ml * sup1;
      }
      ud[(size_t)k*G_+j] = udv; u1[(size_t)k*G_+j] = u1v; u2[(size_t)k*G_+j] = u2v;
      um[(size_t)k*G_+j] = umv; ufl[(size_t)k*G_+j] = flv;
    }
    { double piv = ak; if (fabs(piv) < GU) piv = (piv >= 0.0) ? GU : -GU;
      ud[(size_t)(N_-1)*G_+j] = 1.0 / piv; u1[(size_t)(N_-1)*G_+j] = 0.0; u2[(size_t)(N_-1)*G_+j] = 0.0; }
    for (int i = 0; i < N_; i++) {
      unsigned s = (unsigned)(i * 2654435761u) ^ (unsigned)((j + 1) * 40503u) ^ (unsigned)(b * 2246822519u);
      s = s * 1664525u + 1013904223u;
      s ^= s >> 16; s = s * 2246822519u;
      double rv = ((double)(s >> 8) * (1.0 / 16777216.0)) * 2.0 - 1.0;
      if (fabs(rv) < 1e-3) rv = 0.5;
      yv[(size_t)i*G_+j] = rv;
    }
    for (int it = 0; it < 3; it++) {
      if (it) {
        double mx = 0.0;
        for (int i = 0; i < N_; i++) mx = fmax(mx, fabs(yv[(size_t)i*G_+j]));
        double sc = 1.0 / fmax(mx, 1e-300);
        for (int i = 0; i < N_; i++) yv[(size_t)i*G_+j] *= sc;
      }
      // forward elimination, register-carried
      double ykc = yv[0*G_ + j];
      for (int k = 0; k < N_ - 1; k++) {
        double ynx = yv[(size_t)(k+1)*G_+j];   // original value, not on the chain
        double yk = ykc, yk1 = ynx;
        if (ufl[(size_t)k*G_+j]) { yk = ynx; yk1 = ykc; }
        yk1 -= um[(size_t)k*G_+j] * yk;
        yv[(size_t)k*G_+j] = yk;               // final value for row k
        ykc = yk1;                             // becomes next iteration's yk
      }
      // back substitution: multiply by stored reciprocal (no divides on chain)
      double y1, y2 = 0.0;
      { double tt = ykc * ud[(size_t)(N_-1)*G_+j];
        yv[(size_t)(N_-1)*G_+j] = tt; y1 = tt; }
      for (int k = N_ - 2; k >= 0; k--) {
        double tt = yv[(size_t)k*G_+j] - u1[(size_t)k*G_+j]*y1 - u2[(size_t)k*G_+j]*y2;
        tt *= ud[(size_t)k*G_+j];
        yv[(size_t)k*G_+j] = tt;
        y2 = y1; y1 = tt;
      }
    }
    double s2 = 0.0;
    for (int i = 0; i < N_; i++) { double tt = yv[(size_t)i*G_+j]; s2 += tt * tt; }
    double inv = 1.0 / sqrt(fmax(s2, 1e-300));
    double* Zj = Z + ((size_t)b*G_ + j) * N_;
    for (int i = 0; i < N_; i++) Zj[i] = yv[(size_t)i*G_+j] * inv;
  }
  __syncthreads();
  if (threadIdx.x == 0) {
    double tol = 1e-10 * (fabs(sh_ev[0]) + 1.0);
    cstart[0] = 0;
    for (int q = 1; q < G_; q++)
      cstart[q] = ((sh_ev[q-1] - sh_ev[q]) < tol) ? cstart[q-1] : q;
  }
  __syncthreads();
  for (int q = 1; q < G_; q++) {
    if (cstart[q] == q) continue;
    double* Zq = Z + ((size_t)b*G_ + q) * N_;
    for (int p = cstart[q]; p < q; p++) {
      double* Zp = Z + ((size_t)b*G_ + p) * N_;
      double dp = 0.0;
      for (int i = threadIdx.x; i < N_; i += blockDim.x) dp += Zq[i] * Zp[i];
      for (int o = 32; o > 0; o >>= 1) dp += __shfl_down(dp, o);
      if (threadIdx.x == 0) red0 = dp;
      __syncthreads();
      double dd = red0;
      for (int i = threadIdx.x; i < N_; i += blockDim.x) Zq[i] -= dd * Zp[i];
      __syncthreads();
    }
    double s2 = 0.0;
    for (int i = threadIdx.x; i < N_; i += blockDim.x) { double tt = Zq[i]; s2 += tt * tt; }
    for (int o = 32; o > 0; o >>= 1) s2 += __shfl_down(s2, o);
    if (threadIdx.x == 0) red0 = s2;
    __syncthreads();
    double inv = 1.0 / sqrt(fmax(red0, 1e-300));
    for (int i = threadIdx.x; i < N_; i += blockDim.x) Zq[i] *= inv;
    __syncthreads();
  }
}

// -------- K8: back-transform, one wave per (batch, eigenvector), Z in registers --------
__global__ __launch_bounds__(64) void k_backxf_mb(const double* __restrict__ Aall,
    const double* __restrict__ tauT, double* __restrict__ Z) {
  int blk = blockIdx.x;
  int b = blk / G_, q = blk % G_;
  const double* A = Aall + (size_t)b*N_*N_;
  const double* tau = tauT + (size_t)b*N_;
  double* Zq = Z + ((size_t)b*G_ + q) * N_;
  int lane = threadIdx.x;
  double z[9];
#pragma unroll
  for (int m = 0; m < 9; m++) z[m] = Zq[lane + 64*m];
  for (int k = N_ - 3; k >= 0; k--) {
    double t = tau[k];
    if (t == 0.0) continue;
    const double* vk = A + (size_t)k*N_;
    double vv[9]; double p = 0.0;
#pragma unroll
    for (int m = 0; m < 9; m++) {
      int i = lane + 64*m;
      double vi = (i > k) ? vk[i] : 0.0;
      vv[m] = vi; p += vi * z[m];
    }
    for (int o = 32; o > 0; o >>= 1) p += __shfl_down(p, o);
    p = __shfl(p, 0);
    double s = t * p;
#pragma unroll
    for (int m = 0; m < 9; m++) z[m] -= s * vv[m];
  }
#pragma unroll
  for (int m = 0; m < 9; m++) Zq[lane + 64*m] = z[m];
}

// -------- K9: belong = argmax_q |V[n][q]| (first max) --------
__global__ void k_belong(const double* __restrict__ Z, int* __restrict__ belong) {
  int idx = blockIdx.x * blockDim.x + threadIdx.x;
  if (idx >= B_ * N_) return;
  int b = idx / N_, n = idx % N_;
  const double* Zb = Z + (size_t)b*G_*N_;
  double best = -1.0; int bi = 0;
  for (int q = 0; q < G_; q++) {
    double av = fabs(Zb[(size_t)q*N_ + n]);
    if (av > best) { best = av; bi = q; }
  }
  belong[idx] = bi;
}

// -------- K10: NMS + quota scheduling + index emission (one block per batch) --------
__global__ __launch_bounds__(256) void k_nms(const float* __restrict__ sim,
    const float* __restrict__ cls, const int* __restrict__ belong,
    const float* __restrict__ thrF, float* __restrict__ outF) {
  __shared__ float nsv[N_], rsv[N_];
  __shared__ int bl_s[N_];
  __shared__ int lists[N_];
  __shared__ int off[G_ + 1];
  __shared__ int kc[G_], gc[G_], lowv[G_], upv[G_], tokd[G_], sortg[G_], pre[G_ + 1];
  __shared__ int gathered[L_];
  __shared__ int anyv;
  __shared__ float shthr;
  int b = blockIdx.x, tid = threadIdx.x;
  const float* simb = sim + (size_t)b*N_*N_;
  if (tid == 0) shthr = thrF[b];
  if (tid < G_) gc[tid] = 0;
  __syncthreads();
  for (int i = tid; i < N_; i += 256) {
    int g = belong[b*N_ + i];
    bl_s[i] = g;
    float sc = cls[b*N_ + i];
    nsv[i] = sc; rsv[i] = sc;
    atomicAdd(&gc[g], 1);
  }
  __syncthreads();
  if (tid == 0) {           // deterministic (ascending-n) group list build
    off[0] = 0;
    for (int g = 0; g < G_; g++) off[g+1] = off[g] + gc[g];
    for (int g = 0; g < G_; g++) pre[g] = off[g];
    for (int n = 0; n < N_; n++) lists[pre[bl_s[n]]++] = n;
  }
  __syncthreads();
  float thr = shthr;
  float gs = 1000.0f;
  int myc = 0;
  for (int iter = 0; iter < N_ + 8; iter++) {
    if (tid == 0) anyv = 0;
    __syncthreads();
    int m = -1;
    if (tid < G_) {
      float mx = 0.0f;
      for (int a = off[tid]; a < off[tid+1]; a++) {
        int n2 = lists[a];
        float vv = nsv[n2];
        if (vv > mx) { mx = vv; m = n2; }
      }
      if (m >= 0) anyv = 1;
    }
    __syncthreads();
    if (m >= 0) {
      rsv[m] = gs;
      nsv[m] = 0.0f;
      const float* srow = simb + (size_t)m*N_;
      for (int a = off[tid]; a < off[tid+1]; a++) {
        int n2 = lists[a];
        if (nsv[n2] > 0.0f && srow[n2] > thr) nsv[n2] = 0.0f;
      }
      myc++;
    }
    gs -= 1.0f;
    __syncthreads();
    if (!anyv) break;
  }
  if (tid < G_) kc[tid] = myc;
  __syncthreads();
  if (tid == 0) {
    int sumkc = 0; for (int g = 0; g < G_; g++) sumkc += kc[g];
    int sumlow = 0;
    for (int g = 0; g < G_; g++) {
      lowv[g] = (gc[g] < 1) ? gc[g] : 1;
      int u = 15; if (gc[g] < u) u = gc[g]; if (kc[g] < u) u = kc[g];
      upv[g] = u; sumlow += lowv[g];
    }
    int su = 0; for (int g = 0; g < G_; g++) su += upv[g];
    while (su < NEED_) {
      su = 0;
      for (int g = 0; g < G_; g++) { int u = upv[g] + 1; if (u > gc[g]) u = gc[g]; upv[g] = u; su += u; }
    }
    int other = NEED_ - sumlow - 1; if (other < 0) other = 0;
    float s = (float)sumkc;
    float c = 0.0f; int prevR = 0;
    float otherf = (float)other;
    for (int g = 0; g < G_; g++) {
      float nc = (float)kc[g] / s;
      c += nc;
      int R = (int)rintf(c * otherf);          // round half-to-even like jnp.round
      int od = R - prevR; prevR = R;
      int t0 = od + lowv[g]; if (t0 > upv[g]) t0 = upv[g];
      tokd[g] = t0;
    }
    for (int g = 0; g < G_; g++) sortg[g] = g;
    for (int a = 1; a < G_; a++) {            // stable insertion sort, kc descending
      int vIdx = sortg[a]; int key = kc[vIdx]; int p2 = a - 1;
      while (p2 >= 0 && kc[sortg[p2]] < key) { sortg[p2+1] = sortg[p2]; p2--; }
      sortg[p2+1] = vIdx;
    }
    int target = other + sumlow;
    int sumd = 0; for (int g = 0; g < G_; g++) sumd += tokd[g];
    int fg = 0;
    while (sumd < target) {
      int gi = sortg[(fg < G_-1) ? fg : (G_-1)];
      int fill = upv[gi] - tokd[gi];
      int rem = target - sumd;
      if (rem < fill) fill = rem;
      tokd[gi] += fill; sumd += fill;
      fg++;
      if (fg > 100000) break;
    }
    pre[0] = 0; for (int g = 0; g < G_; g++) pre[g+1] = pre[g] + tokd[g];
  }
  __syncthreads();
  for (int i = tid; i < L_; i += 256) gathered[i] = 0;
  __syncthreads();
  if (tid < G_) {
    int g = tid;
    int td = tokd[g], base = pre[g];
    for (int t = 0; t < td; t++) {
      float bv = -3e38f; int bn2 = 0;
      for (int a = off[g]; a < off[g+1]; a++) {
        int n2 = lists[a];
        float vv = rsv[n2];
        if (vv > bv) { bv = vv; bn2 = n2; }
      }
      rsv[bn2] = -3e38f;
      int pos = base + t;
      if (pos < L_) gathered[pos] = bn2;
    }
  }
  __syncthreads();
  if (tid < NEED_) {
    float val = (tid == 0) ? 0.0f : (float)(gathered[tid - 1] + 1);
    outF[(size_t)B_*NEED_*D_ + (size_t)b*NEED_ + tid] = val;
  }
}

// -------- K11: gather selected hidden rows --------
__global__ void k_gather(const float* __restrict__ hs, float* __restrict__ outF) {
  int blk = blockIdx.x;
  int b = blk / NEED_, i = blk % NEED_;
  int idx = (int)outF[(size_t)B_*NEED_*D_ + (size_t)b*NEED_ + i];
  const float4* src = (const float4*)(hs + ((size_t)b*T_ + idx) * (size_t)D_);
  float4* dst = (float4*)(outF + ((size_t)b*NEED_ + i) * (size_t)D_);
  dst[threadIdx.x] = src[threadIdx.x];
}

extern "C" void kernel_launch(void* const* d_in, const int* in_sizes, int n_in,
                              void* d_out, int out_size, void* d_ws, size_t ws_size,
                              hipStream_t stream) {
  if (ws_size < WS_NEEDED) return;
  const float* hs   = (const float*)d_in[0];
  const float* attn = (const float*)d_in[1];
  float* outF = (float*)d_out;
  char* w = (char*)d_ws;
  float*  msig = (float*)(w + OF_MSIG);
  float*  sim  = (float*)(w + OF_SIM);
  double* A    = (double*)(w + OF_A);
  double* ms   = (double*)(w + OF_MS);
  double* invn = (double*)(w + OF_INVN);
  float*  cls  = (float*)(w + OF_CLS);
  double* dT   = (double*)(w + OF_DT);
  double* eT   = (double*)(w + OF_ET);
  double* tauT = (double*)(w + OF_TAU);
  double* eval = (double*)(w + OF_EVAL);
  double* Z    = (double*)(w + OF_Z);
  double* part = (double*)(w + OF_PART);
  float*  thrF = (float*)(w + OF_THR);
  int*    belong = (int*)(w + OF_BEL);
  int*    bars = (int*)(w + OF_BAR);
  double* wb   = (double*)(w + OF_WB);
  double* pv   = (double*)(w + OF_PV_ALIAS);   // dead msig region during tridiag
  // inverse-iteration scratch aliases msig region (msig dead after the Gram GEMM)
  double* Ud = (double*)(w + OF_MSIG);
  double* U1 = Ud + (size_t)B_*N_*G_;
  double* U2 = U1 + (size_t)B_*N_*G_;
  double* Um = U2 + (size_t)B_*N_*G_;
  double* Yv = Um + (size_t)B_*N_*G_;
  int*    Ufl = (int*)(Yv + (size_t)B_*N_*G_);

  k_prep<<<B_*N_, 256, 0, stream>>>(hs, msig, ms, invn, bars);
  k_gemm<<<dim3(N_/32, N_/32, B_), 256, 0, stream>>>(hs, msig, ms, invn, A, sim, 0);
  k_tridiag_mb<<<FUSED_BLKS, 512, 0, stream>>>(A, dT, eT, tauT, pv, wb, bars,
                                               hs, invn, sim, attn, cls);
  k_simsum<<<B_*36, 256, 0, stream>>>(sim, part);
  k_thr<<<1, 64, 0, stream>>>(part, thrF);
  k_eigvals_ms<<<B_*G_, 64, 0, stream>>>(dT, eT, eval);
  k_eigvecs<<<B_, 64, 0, stream>>>(dT, eT, eval, Ud, U1, U2, Um, Ufl, Yv, Z);
  k_backxf_mb<<<B_*G_, 64, 0, stream>>>(A, tauT, Z);
  k_belong<<<(B_*N_ + 255)/256, 256, 0, stream>>>(Z, belong);
  k_nms<<<B_, 256, 0, stream>>>(sim, cls, belong, thrF, outF);
  k_gather<<<B_*NEED_, 256, 0, stream>>>(hs, outF);
}